// Round 1
// baseline (3856.694 us; speedup 1.0000x reference)
//
#include <hip/hip_runtime.h>

#define N_NODES 100000
#define N_EDGES 3200000
#define IN_C 602
#define HID_C 256
#define OUTC 41
#define K_ITERS 10

#define BR 32
#define KT 16

// ---------------- degree ----------------
__global__ __launch_bounds__(256) void deg_kernel(const int* __restrict__ col,
                                                  unsigned* __restrict__ deg) {
  int e = blockIdx.x * 256 + threadIdx.x;
  if (e < N_EDGES) atomicAdd(&deg[col[e]], 1u);
}

__global__ __launch_bounds__(256) void dinv_kernel(const unsigned* __restrict__ deg,
                                                   float* __restrict__ dinv) {
  int i = blockIdx.x * 256 + threadIdx.x;
  if (i < N_NODES) dinv[i] = rsqrtf((float)(deg[i] + 1u));
}

// ---------------- fused MLP + L2 normalize ----------------
// h0 = normalize_rows( relu(x@W1^T + b1) @ W2^T + b2 )
__global__ __launch_bounds__(256) void mlp_kernel(const float* __restrict__ x,
                                                  const float* __restrict__ W1,
                                                  const float* __restrict__ b1,
                                                  const float* __restrict__ W2,
                                                  const float* __restrict__ b2,
                                                  float* __restrict__ H0) {
  __shared__ float xs[KT][BR + 4];       // [k][row], padded for b128 align
  __shared__ float ws[KT][HID_C + 1];    // [k][col], padded for bank-conflict-free
  __shared__ float h1s[BR][HID_C + 4];   // relu(h1), stride 260
  __shared__ float h2s[BR][OUTC];
  __shared__ float rnorm[BR];

  const int t = threadIdx.x;
  const int r0 = blockIdx.x * BR;

  const int rg = t >> 5;   // 0..7 -> rows rg*4..+3
  const int cg = t & 31;   // cols cg + 32*j, j=0..7

  float acc[4][8];
#pragma unroll
  for (int j = 0; j < 8; ++j) {
    float bj = b1[cg + 32 * j];
#pragma unroll
    for (int i = 0; i < 4; ++i) acc[i][j] = bj;
  }

  for (int k0 = 0; k0 < IN_C; k0 += KT) {
    // load x tile transposed: xs[k][r]
    for (int idx = t; idx < KT * BR; idx += 256) {
      int k = idx & (KT - 1), r = idx >> 4;
      int gr = r0 + r, gk = k0 + k;
      xs[k][r] = (gr < N_NODES && gk < IN_C) ? x[gr * IN_C + gk] : 0.f;
    }
    // load W1 tile transposed: ws[k][c] = W1[c][k0+k]; thread t owns row c=t
    {
      const int c = t;
#pragma unroll
      for (int k = 0; k < KT; ++k) {
        int gk = k0 + k;
        ws[k][c] = (gk < IN_C) ? W1[c * IN_C + gk] : 0.f;
      }
    }
    __syncthreads();
#pragma unroll
    for (int k = 0; k < KT; ++k) {
      float4 xv = *(const float4*)&xs[k][rg * 4];
      float wv[8];
#pragma unroll
      for (int j = 0; j < 8; ++j) wv[j] = ws[k][cg + 32 * j];
#pragma unroll
      for (int j = 0; j < 8; ++j) {
        acc[0][j] += xv.x * wv[j];
        acc[1][j] += xv.y * wv[j];
        acc[2][j] += xv.z * wv[j];
        acc[3][j] += xv.w * wv[j];
      }
    }
    __syncthreads();
  }

  // write relu(h1) into LDS
#pragma unroll
  for (int i = 0; i < 4; ++i)
#pragma unroll
    for (int j = 0; j < 8; ++j)
      h1s[rg * 4 + i][cg + 32 * j] = fmaxf(acc[i][j], 0.f);
  __syncthreads();

  // phase B: h2 = h1 @ W2^T + b2
  {
    const int r = t & 31;
    const int cgB = t >> 5;  // 8 groups
    const float4* hv = (const float4*)&h1s[r][0];
    for (int c = cgB; c < OUTC; c += 8) {
      float a = b2[c];
      const float4* w2v = (const float4*)(W2 + c * HID_C);
#pragma unroll
      for (int k4 = 0; k4 < HID_C / 4; ++k4) {
        float4 hh = hv[k4];
        float4 ww = w2v[k4];
        a += hh.x * ww.x + hh.y * ww.y + hh.z * ww.z + hh.w * ww.w;
      }
      h2s[r][c] = a;
    }
  }
  __syncthreads();

  if (t < BR) {
    float s = 0.f;
    for (int c = 0; c < OUTC; ++c) s += h2s[t][c] * h2s[t][c];
    rnorm[t] = 1.f / fmaxf(sqrtf(s), 1e-12f);
  }
  __syncthreads();

  for (int idx = t; idx < BR * OUTC; idx += 256) {
    int r = idx / OUTC, c = idx % OUTC;
    int gr = r0 + r;
    if (gr < N_NODES) H0[gr * OUTC + c] = h2s[r][c] * rnorm[r];
  }
}

// ---------------- exclusive scan (3 kernels) ----------------
__global__ __launch_bounds__(256) void scan1_kernel(const unsigned* __restrict__ deg,
                                                    unsigned* __restrict__ offs,
                                                    unsigned* __restrict__ btot) {
  __shared__ unsigned wsum[4];
  __shared__ unsigned wbase[4];
  const int t = threadIdx.x, lane = t & 63, w = t >> 6;
  const int base = blockIdx.x * 1024 + t * 4;
  unsigned v[4];
#pragma unroll
  for (int i = 0; i < 4; ++i) {
    int idx = base + i;
    v[i] = (idx < N_NODES) ? deg[idx] : 0u;
  }
  unsigned tsum = v[0] + v[1] + v[2] + v[3];
  unsigned inc = tsum;
  for (int d = 1; d < 64; d <<= 1) {
    unsigned n = (unsigned)__shfl_up((int)inc, d);
    if (lane >= d) inc += n;
  }
  if (lane == 63) wsum[w] = inc;
  __syncthreads();
  if (t == 0) {
    unsigned run = 0;
    for (int i = 0; i < 4; ++i) { unsigned s = wsum[i]; wbase[i] = run; run += s; }
    btot[blockIdx.x] = run;
  }
  __syncthreads();
  unsigned ex = wbase[w] + inc - tsum;
#pragma unroll
  for (int i = 0; i < 4; ++i) {
    int idx = base + i;
    if (idx < N_NODES) offs[idx] = ex;
    ex += v[i];
  }
}

__global__ __launch_bounds__(128) void scan2_kernel(const unsigned* __restrict__ btot,
                                                    unsigned* __restrict__ bbase, int B) {
  __shared__ unsigned wsum[2];
  __shared__ unsigned wbase[2];
  const int t = threadIdx.x, lane = t & 63, w = t >> 6;
  unsigned v = (t < B) ? btot[t] : 0u;
  unsigned inc = v;
  for (int d = 1; d < 64; d <<= 1) {
    unsigned n = (unsigned)__shfl_up((int)inc, d);
    if (lane >= d) inc += n;
  }
  if (lane == 63) wsum[w] = inc;
  __syncthreads();
  if (t == 0) {
    unsigned run = 0;
    for (int i = 0; i < 2; ++i) { unsigned s = wsum[i]; wbase[i] = run; run += s; }
  }
  __syncthreads();
  unsigned ex = wbase[w] + inc - v;
  if (t < B) bbase[t] = ex;
}

__global__ __launch_bounds__(256) void scan3_kernel(unsigned* __restrict__ offs,
                                                    const unsigned* __restrict__ bbase) {
  int i = blockIdx.x * 256 + threadIdx.x;
  if (i < N_NODES) offs[i] += bbase[i >> 10];
}

// ---------------- CSC scatter ----------------
__global__ __launch_bounds__(256) void scatter_kernel(const int* __restrict__ row,
                                                      const int* __restrict__ col,
                                                      const float* __restrict__ dinv,
                                                      const unsigned* __restrict__ offs,
                                                      unsigned* __restrict__ cursor,
                                                      int2* __restrict__ rec) {
  int e = blockIdx.x * 256 + threadIdx.x;
  if (e >= N_EDGES) return;
  int r = row[e], c = col[e];
  float wgt = dinv[r] * dinv[c];
  unsigned pos = offs[c] + atomicAdd(&cursor[c], 1u);
  rec[pos] = make_int2(r, __float_as_int(wgt));
}

// ---------------- APPNP iteration (gather form) ----------------
__global__ __launch_bounds__(256) void prop_kernel(const float* __restrict__ hsrc,
                                                   const float* __restrict__ h0,
                                                   float* __restrict__ hdst,
                                                   const int2* __restrict__ rec,
                                                   const unsigned* __restrict__ offs,
                                                   const unsigned* __restrict__ deg,
                                                   const float* __restrict__ dinv) {
  const int w = threadIdx.x >> 6;
  const int lane = threadIdx.x & 63;
  const int n = blockIdx.x * 4 + w;
  if (n >= N_NODES) return;
  const int cc = (lane < OUTC) ? lane : 0;
  const unsigned s = offs[n];
  const unsigned e = s + deg[n];
  float acc = 0.f;
  unsigned i = s;
  for (; i + 4 <= e; i += 4) {
    int2 r0 = rec[i], r1 = rec[i + 1], r2 = rec[i + 2], r3 = rec[i + 3];
    float a0 = hsrc[r0.x * OUTC + cc];
    float a1 = hsrc[r1.x * OUTC + cc];
    float a2 = hsrc[r2.x * OUTC + cc];
    float a3 = hsrc[r3.x * OUTC + cc];
    acc += a0 * __int_as_float(r0.y);
    acc += a1 * __int_as_float(r1.y);
    acc += a2 * __int_as_float(r2.y);
    acc += a3 * __int_as_float(r3.y);
  }
  for (; i < e; ++i) {
    int2 r = rec[i];
    acc += hsrc[r.x * OUTC + cc] * __int_as_float(r.y);
  }
  float di = dinv[n];
  acc += hsrc[n * OUTC + cc] * di * di;       // self-loop
  float o = 0.9f * acc + 0.1f * h0[n * OUTC + cc];
  if (lane < OUTC) hdst[n * OUTC + lane] = o;
}

// ---------------- host ----------------
extern "C" void kernel_launch(void* const* d_in, const int* in_sizes, int n_in,
                              void* d_out, int out_size, void* d_ws, size_t ws_size,
                              hipStream_t stream) {
  const float* x  = (const float*)d_in[0];
  const int*   ei = (const int*)d_in[1];
  const float* W1 = (const float*)d_in[2];
  const float* b1 = (const float*)d_in[3];
  const float* W2 = (const float*)d_in[4];
  const float* b2 = (const float*)d_in[5];
  float* out = (float*)d_out;

  char* p = (char*)d_ws;
  auto alloc = [&](size_t bytes) {
    char* q = p;
    p += (bytes + 255) & ~(size_t)255;
    return q;
  };
  unsigned* deg    = (unsigned*)alloc((size_t)N_NODES * 4);
  float*    dinv   = (float*)   alloc((size_t)N_NODES * 4);
  unsigned* offs   = (unsigned*)alloc((size_t)N_NODES * 4);
  unsigned* btot   = (unsigned*)alloc(128 * 4);
  unsigned* bbase  = (unsigned*)alloc(128 * 4);
  unsigned* cursor = (unsigned*)alloc((size_t)N_NODES * 4);
  int2*     rec    = (int2*)    alloc((size_t)N_EDGES * 8);
  float*    H0     = (float*)   alloc((size_t)N_NODES * OUTC * 4);
  float*    HB     = (float*)   alloc((size_t)N_NODES * OUTC * 4);

  const int* row = ei;            // edge_index[0] : sources
  const int* col = ei + N_EDGES;  // edge_index[1] : targets

  hipMemsetAsync(deg, 0, (size_t)N_NODES * 4, stream);
  hipMemsetAsync(cursor, 0, (size_t)N_NODES * 4, stream);

  deg_kernel<<<(N_EDGES + 255) / 256, 256, 0, stream>>>(col, deg);
  dinv_kernel<<<(N_NODES + 255) / 256, 256, 0, stream>>>(deg, dinv);
  mlp_kernel<<<(N_NODES + BR - 1) / BR, 256, 0, stream>>>(x, W1, b1, W2, b2, H0);

  const int B = (N_NODES + 1023) / 1024;  // 98
  scan1_kernel<<<B, 256, 0, stream>>>(deg, offs, btot);
  scan2_kernel<<<1, 128, 0, stream>>>(btot, bbase, B);
  scan3_kernel<<<(N_NODES + 255) / 256, 256, 0, stream>>>(offs, bbase);
  scatter_kernel<<<(N_EDGES + 255) / 256, 256, 0, stream>>>(row, col, dinv, offs, cursor, rec);

  const float* src = H0;
  for (int k = 0; k < K_ITERS; ++k) {
    float* dst = (k == K_ITERS - 1) ? out : ((k & 1) ? out : HB);
    prop_kernel<<<(N_NODES + 3) / 4, 256, 0, stream>>>(src, H0, dst, rec, offs, deg, dinv);
    src = dst;
  }
}

// Round 2
// 2138.611 us; speedup vs baseline: 1.8034x; 1.8034x over previous
//
#include <hip/hip_runtime.h>

#define N_NODES 100000
#define N_EDGES 3200000
#define IN_C 602
#define KPAD 608
#define HID_C 256
#define OUTC 41
#define K_ITERS 10

typedef __attribute__((ext_vector_type(8))) short bf16x8;
typedef __attribute__((ext_vector_type(4))) float f32x4;

static __device__ __forceinline__ unsigned short f2bf(float f) {
  unsigned u = __float_as_uint(f);
  u += 0x7fffu + ((u >> 16) & 1u);
  return (unsigned short)(u >> 16);
}
static __device__ __forceinline__ float bf2f(unsigned short h) {
  return __uint_as_float(((unsigned)h) << 16);
}

// ---------------- degree ----------------
__global__ __launch_bounds__(256) void deg_kernel(const int* __restrict__ col,
                                                  unsigned* __restrict__ deg) {
  int e = blockIdx.x * 256 + threadIdx.x;
  if (e < N_EDGES) atomicAdd(&deg[col[e]], 1u);
}

__global__ __launch_bounds__(256) void dinv_kernel(const unsigned* __restrict__ deg,
                                                   float* __restrict__ dinv) {
  int i = blockIdx.x * 256 + threadIdx.x;
  if (i < N_NODES) dinv[i] = rsqrtf((float)(deg[i] + 1u));
}

// ---------------- W1 bf16 hi/lo split (one-time, 623 KB) ----------------
__global__ __launch_bounds__(256) void wprep_kernel(const float* __restrict__ W1,
                                                    unsigned short* __restrict__ Wh,
                                                    unsigned short* __restrict__ Wl) {
  int idx = blockIdx.x * 256 + threadIdx.x;
  if (idx >= HID_C * KPAD) return;
  int n = idx / KPAD, k = idx % KPAD;
  float v = (k < IN_C) ? W1[n * IN_C + k] : 0.f;
  unsigned short hi = f2bf(v);
  Wh[idx] = hi;
  Wl[idx] = f2bf(v - bf2f(hi));
}

// ---------------- fused MLP (bf16x3 MFMA GEMM1 + fp32 GEMM2 + L2 norm) ----
__global__ __launch_bounds__(256, 2) void mlp_kernel(
    const float* __restrict__ x,
    const unsigned short* __restrict__ Wh, const unsigned short* __restrict__ Wl,
    const float* __restrict__ b1,
    const float* __restrict__ W2, const float* __restrict__ b2,
    float* __restrict__ H0) {
  __shared__ short Ah[64 * 32];            // bf16 hi tile, fragment-linear chunks
  __shared__ short Al[64 * 32];            // bf16 lo tile
  __shared__ unsigned short h1s[64 * 264]; // relu(h1) bf16, row stride 264
  __shared__ float W2s[41][68];
  __shared__ float psum[64][4];
  __shared__ float rnorm[64];

  const int tid = threadIdx.x;
  const int lane = tid & 63;
  const int w = tid >> 6;
  const int r0 = blockIdx.x * 64;

  // A-stage: thread tid produces 16B chunk `tid` = row (tid>>6)*16+(tid&15),
  // k-slot ((tid>>4)&3)*8  (matches read pattern chunk = mt*64 + lane)
  const int arow = ((tid >> 6) << 4) | (tid & 15);
  const int akoff = ((tid >> 4) & 3) << 3;
  const int gr_ld = r0 + arow;

  // B fragment addressing (global, L2-resident)
  const int bcol0 = (w << 6) + (lane & 15);
  const int bko = (lane >> 4) << 3;

  f32x4 acc[4][4];
#pragma unroll
  for (int s = 0; s < 4; ++s) {
    float bv = b1[bcol0 + s * 16];
#pragma unroll
    for (int mi = 0; mi < 4; ++mi) acc[mi][s] = (f32x4){bv, bv, bv, bv};
  }

  for (int t = 0; t < KPAD / 32; ++t) {
    const int kb = t * 32 + akoff;
    float v[8];
    if (gr_ld < N_NODES && kb + 8 <= IN_C) {
      const float* px = x + (size_t)gr_ld * IN_C + kb;
      float2 p0 = *(const float2*)(px + 0);
      float2 p1 = *(const float2*)(px + 2);
      float2 p2 = *(const float2*)(px + 4);
      float2 p3 = *(const float2*)(px + 6);
      v[0] = p0.x; v[1] = p0.y; v[2] = p1.x; v[3] = p1.y;
      v[4] = p2.x; v[5] = p2.y; v[6] = p3.x; v[7] = p3.y;
    } else {
#pragma unroll
      for (int j = 0; j < 8; ++j) {
        int k = kb + j;
        v[j] = (gr_ld < N_NODES && k < IN_C) ? x[(size_t)gr_ld * IN_C + k] : 0.f;
      }
    }
    union { unsigned short u[8]; bf16x8 vec; } up, lp;
#pragma unroll
    for (int j = 0; j < 8; ++j) {
      unsigned short hi = f2bf(v[j]);
      up.u[j] = hi;
      lp.u[j] = f2bf(v[j] - bf2f(hi));
    }
    __syncthreads();  // previous ktile's ds_reads complete
    *(bf16x8*)&Ah[tid * 8] = up.vec;
    *(bf16x8*)&Al[tid * 8] = lp.vec;
    __syncthreads();

    bf16x8 bh[4], bl[4], ah[4], al[4];
    const int kgb = t * 32 + bko;
#pragma unroll
    for (int s = 0; s < 4; ++s) {
      const int n = bcol0 + s * 16;
      bh[s] = *(const bf16x8*)(Wh + (size_t)n * KPAD + kgb);
      bl[s] = *(const bf16x8*)(Wl + (size_t)n * KPAD + kgb);
    }
#pragma unroll
    for (int mi = 0; mi < 4; ++mi) {
      ah[mi] = *(const bf16x8*)&Ah[(mi * 64 + lane) * 8];
      al[mi] = *(const bf16x8*)&Al[(mi * 64 + lane) * 8];
    }
#pragma unroll
    for (int mi = 0; mi < 4; ++mi)
#pragma unroll
      for (int s = 0; s < 4; ++s) {
        acc[mi][s] = __builtin_amdgcn_mfma_f32_16x16x32_bf16(ah[mi], bh[s], acc[mi][s], 0, 0, 0);
        acc[mi][s] = __builtin_amdgcn_mfma_f32_16x16x32_bf16(al[mi], bh[s], acc[mi][s], 0, 0, 0);
        acc[mi][s] = __builtin_amdgcn_mfma_f32_16x16x32_bf16(ah[mi], bl[s], acc[mi][s], 0, 0, 0);
      }
  }

  // write relu(h1) as bf16 into LDS (C layout: row=(lane>>4)*4+q, col=lane&15)
#pragma unroll
  for (int mi = 0; mi < 4; ++mi)
#pragma unroll
    for (int s = 0; s < 4; ++s)
#pragma unroll
      for (int q = 0; q < 4; ++q) {
        int rr = mi * 16 + ((lane >> 4) << 2) + q;
        int cc = (w << 6) + s * 16 + (lane & 15);
        h1s[rr * 264 + cc] = f2bf(fmaxf(acc[mi][s][q], 0.f));
      }
  __syncthreads();

  // phase B: h2 = h1 @ W2^T + b2, then L2-normalize rows
  const int br = tid & 63;
  const int cg = w;
  const int nj = (cg == 0) ? 11 : 10;
  float outs[11];
#pragma unroll
  for (int j = 0; j < 11; ++j) {
    int c = cg + 4 * j;
    outs[j] = (c < OUTC) ? b2[c] : 0.f;
  }

  for (int kc = 0; kc < 4; ++kc) {
    for (int e = tid; e < OUTC * 64; e += 256) {
      int c = e >> 6, kk = e & 63;
      W2s[c][kk] = W2[c * HID_C + kc * 64 + kk];
    }
    __syncthreads();
#pragma unroll 4
    for (int kk = 0; kk < 64; kk += 4) {
      const ushort4 hv = *(const ushort4*)&h1s[br * 264 + kc * 64 + kk];
      float h0v = bf2f(hv.x), h1v = bf2f(hv.y), h2v = bf2f(hv.z), h3v = bf2f(hv.w);
      for (int j = 0; j < nj; ++j) {
        const float4 wv = *(const float4*)&W2s[cg + 4 * j][kk];
        outs[j] += h0v * wv.x + h1v * wv.y + h2v * wv.z + h3v * wv.w;
      }
    }
    __syncthreads();
  }

  float ss = 0.f;
  for (int j = 0; j < nj; ++j) ss += outs[j] * outs[j];
  psum[br][cg] = ss;
  __syncthreads();
  if (tid < 64) {
    float s = psum[tid][0] + psum[tid][1] + psum[tid][2] + psum[tid][3];
    rnorm[tid] = 1.f / fmaxf(sqrtf(s), 1e-12f);
  }
  __syncthreads();
  const int gr = r0 + br;
  if (gr < N_NODES) {
    float rn = rnorm[br];
    for (int j = 0; j < nj; ++j) H0[(size_t)gr * OUTC + cg + 4 * j] = outs[j] * rn;
  }
}

// ---------------- exclusive scan (3 kernels) ----------------
__global__ __launch_bounds__(256) void scan1_kernel(const unsigned* __restrict__ deg,
                                                    unsigned* __restrict__ offs,
                                                    unsigned* __restrict__ btot) {
  __shared__ unsigned wsum[4];
  __shared__ unsigned wbase[4];
  const int t = threadIdx.x, lane = t & 63, w = t >> 6;
  const int base = blockIdx.x * 1024 + t * 4;
  unsigned v[4];
#pragma unroll
  for (int i = 0; i < 4; ++i) {
    int idx = base + i;
    v[i] = (idx < N_NODES) ? deg[idx] : 0u;
  }
  unsigned tsum = v[0] + v[1] + v[2] + v[3];
  unsigned inc = tsum;
  for (int d = 1; d < 64; d <<= 1) {
    unsigned n = (unsigned)__shfl_up((int)inc, d);
    if (lane >= d) inc += n;
  }
  if (lane == 63) wsum[w] = inc;
  __syncthreads();
  if (t == 0) {
    unsigned run = 0;
    for (int i = 0; i < 4; ++i) { unsigned s = wsum[i]; wbase[i] = run; run += s; }
    btot[blockIdx.x] = run;
  }
  __syncthreads();
  unsigned ex = wbase[w] + inc - tsum;
#pragma unroll
  for (int i = 0; i < 4; ++i) {
    int idx = base + i;
    if (idx < N_NODES) offs[idx] = ex;
    ex += v[i];
  }
}

__global__ __launch_bounds__(128) void scan2_kernel(const unsigned* __restrict__ btot,
                                                    unsigned* __restrict__ bbase, int B) {
  __shared__ unsigned wsum[2];
  __shared__ unsigned wbase[2];
  const int t = threadIdx.x, lane = t & 63, w = t >> 6;
  unsigned v = (t < B) ? btot[t] : 0u;
  unsigned inc = v;
  for (int d = 1; d < 64; d <<= 1) {
    unsigned n = (unsigned)__shfl_up((int)inc, d);
    if (lane >= d) inc += n;
  }
  if (lane == 63) wsum[w] = inc;
  __syncthreads();
  if (t == 0) {
    unsigned run = 0;
    for (int i = 0; i < 2; ++i) { unsigned s = wsum[i]; wbase[i] = run; run += s; }
  }
  __syncthreads();
  unsigned ex = wbase[w] + inc - v;
  if (t < B) bbase[t] = ex;
}

__global__ __launch_bounds__(256) void scan3_kernel(unsigned* __restrict__ offs,
                                                    const unsigned* __restrict__ bbase) {
  int i = blockIdx.x * 256 + threadIdx.x;
  if (i < N_NODES) offs[i] += bbase[i >> 10];
}

// ---------------- CSC scatter ----------------
__global__ __launch_bounds__(256) void scatter_kernel(const int* __restrict__ row,
                                                      const int* __restrict__ col,
                                                      const float* __restrict__ dinv,
                                                      const unsigned* __restrict__ offs,
                                                      unsigned* __restrict__ cursor,
                                                      int2* __restrict__ rec) {
  int e = blockIdx.x * 256 + threadIdx.x;
  if (e >= N_EDGES) return;
  int r = row[e], c = col[e];
  float wgt = dinv[r] * dinv[c];
  unsigned pos = offs[c] + atomicAdd(&cursor[c], 1u);
  rec[pos] = make_int2(r, __float_as_int(wgt));
}

// ---------------- APPNP iteration (gather form) ----------------
__global__ __launch_bounds__(256) void prop_kernel(const float* __restrict__ hsrc,
                                                   const float* __restrict__ h0,
                                                   float* __restrict__ hdst,
                                                   const int2* __restrict__ rec,
                                                   const unsigned* __restrict__ offs,
                                                   const unsigned* __restrict__ deg,
                                                   const float* __restrict__ dinv) {
  const int w = threadIdx.x >> 6;
  const int lane = threadIdx.x & 63;
  const int n = blockIdx.x * 4 + w;
  if (n >= N_NODES) return;
  const int cc = (lane < OUTC) ? lane : 0;
  const unsigned s = offs[n];
  const unsigned e = s + deg[n];
  float acc = 0.f;
  unsigned i = s;
  for (; i + 4 <= e; i += 4) {
    int2 r0 = rec[i], r1 = rec[i + 1], r2 = rec[i + 2], r3 = rec[i + 3];
    float a0 = hsrc[r0.x * OUTC + cc];
    float a1 = hsrc[r1.x * OUTC + cc];
    float a2 = hsrc[r2.x * OUTC + cc];
    float a3 = hsrc[r3.x * OUTC + cc];
    acc += a0 * __int_as_float(r0.y);
    acc += a1 * __int_as_float(r1.y);
    acc += a2 * __int_as_float(r2.y);
    acc += a3 * __int_as_float(r3.y);
  }
  for (; i < e; ++i) {
    int2 r = rec[i];
    acc += hsrc[r.x * OUTC + cc] * __int_as_float(r.y);
  }
  float di = dinv[n];
  acc += hsrc[n * OUTC + cc] * di * di;       // self-loop
  float o = 0.9f * acc + 0.1f * h0[n * OUTC + cc];
  if (lane < OUTC) hdst[n * OUTC + lane] = o;
}

// ---------------- host ----------------
extern "C" void kernel_launch(void* const* d_in, const int* in_sizes, int n_in,
                              void* d_out, int out_size, void* d_ws, size_t ws_size,
                              hipStream_t stream) {
  const float* x  = (const float*)d_in[0];
  const int*   ei = (const int*)d_in[1];
  const float* W1 = (const float*)d_in[2];
  const float* b1 = (const float*)d_in[3];
  const float* W2 = (const float*)d_in[4];
  const float* b2 = (const float*)d_in[5];
  float* out = (float*)d_out;

  char* p = (char*)d_ws;
  auto alloc = [&](size_t bytes) {
    char* q = p;
    p += (bytes + 255) & ~(size_t)255;
    return q;
  };
  unsigned* deg    = (unsigned*)alloc((size_t)N_NODES * 4);
  float*    dinv   = (float*)   alloc((size_t)N_NODES * 4);
  unsigned* offs   = (unsigned*)alloc((size_t)N_NODES * 4);
  unsigned* btot   = (unsigned*)alloc(128 * 4);
  unsigned* bbase  = (unsigned*)alloc(128 * 4);
  unsigned* cursor = (unsigned*)alloc((size_t)N_NODES * 4);
  int2*     rec    = (int2*)    alloc((size_t)N_EDGES * 8);
  float*    H0     = (float*)   alloc((size_t)N_NODES * OUTC * 4);
  float*    HB     = (float*)   alloc((size_t)N_NODES * OUTC * 4);
  unsigned short* Wh = (unsigned short*)alloc((size_t)HID_C * KPAD * 2);
  unsigned short* Wl = (unsigned short*)alloc((size_t)HID_C * KPAD * 2);

  const int* row = ei;            // edge_index[0] : sources
  const int* col = ei + N_EDGES;  // edge_index[1] : targets

  hipMemsetAsync(deg, 0, (size_t)N_NODES * 4, stream);
  hipMemsetAsync(cursor, 0, (size_t)N_NODES * 4, stream);

  deg_kernel<<<(N_EDGES + 255) / 256, 256, 0, stream>>>(col, deg);
  dinv_kernel<<<(N_NODES + 255) / 256, 256, 0, stream>>>(deg, dinv);
  wprep_kernel<<<(HID_C * KPAD + 255) / 256, 256, 0, stream>>>(W1, Wh, Wl);
  mlp_kernel<<<(N_NODES + 63) / 64, 256, 0, stream>>>(x, Wh, Wl, b1, W2, b2, H0);

  const int B = (N_NODES + 1023) / 1024;  // 98
  scan1_kernel<<<B, 256, 0, stream>>>(deg, offs, btot);
  scan2_kernel<<<1, 128, 0, stream>>>(btot, bbase, B);
  scan3_kernel<<<(N_NODES + 255) / 256, 256, 0, stream>>>(offs, bbase);
  scatter_kernel<<<(N_EDGES + 255) / 256, 256, 0, stream>>>(row, col, dinv, offs, cursor, rec);

  const float* src = H0;
  for (int k = 0; k < K_ITERS; ++k) {
    float* dst = (k == K_ITERS - 1) ? out : ((k & 1) ? out : HB);
    prop_kernel<<<(N_NODES + 3) / 4, 256, 0, stream>>>(src, H0, dst, rec, offs, deg, dinv);
    src = dst;
  }
}

// Round 3
// 1939.882 us; speedup vs baseline: 1.9881x; 1.1024x over previous
//
#include <hip/hip_runtime.h>

#define N_NODES 100000
#define N_EDGES 3200000
#define IN_C 602
#define KPAD 608
#define NT (KPAD / 32)  // 19
#define HID_C 256
#define OUTC 41
#define PADC 48
#define K_ITERS 10

typedef __attribute__((ext_vector_type(8))) short bf16x8;
typedef __attribute__((ext_vector_type(4))) float f32x4;

static __device__ __forceinline__ unsigned short f2bf(float f) {
  unsigned u = __float_as_uint(f);
  u += 0x7fffu + ((u >> 16) & 1u);
  return (unsigned short)(u >> 16);
}
static __device__ __forceinline__ float bf2f(unsigned short h) {
  return __uint_as_float(((unsigned)h) << 16);
}

// ---------------- degree ----------------
__global__ __launch_bounds__(256) void deg_kernel(const int* __restrict__ col,
                                                  unsigned* __restrict__ deg) {
  int e = blockIdx.x * 256 + threadIdx.x;
  if (e < N_EDGES) atomicAdd(&deg[col[e]], 1u);
}

__global__ __launch_bounds__(256) void dinv_kernel(const unsigned* __restrict__ deg,
                                                   float* __restrict__ dinv) {
  int i = blockIdx.x * 256 + threadIdx.x;
  if (i < N_NODES) dinv[i] = rsqrtf((float)(deg[i] + 1u));
}

// ---------------- W1 bf16 hi/lo split (one-time, 623 KB) ----------------
__global__ __launch_bounds__(256) void wprep_kernel(const float* __restrict__ W1,
                                                    unsigned short* __restrict__ Wh,
                                                    unsigned short* __restrict__ Wl) {
  int idx = blockIdx.x * 256 + threadIdx.x;
  if (idx >= HID_C * KPAD) return;
  int n = idx / KPAD, k = idx % KPAD;
  float v = (k < IN_C) ? W1[n * IN_C + k] : 0.f;
  unsigned short hi = f2bf(v);
  Wh[idx] = hi;
  Wl[idx] = f2bf(v - bf2f(hi));
}

// ---------------- fused MLP (pipelined bf16x3 MFMA GEMM1 + fp32 GEMM2) ----
__global__ __launch_bounds__(256, 2) void mlp_kernel(
    const float* __restrict__ x,
    const unsigned short* __restrict__ Wh, const unsigned short* __restrict__ Wl,
    const float* __restrict__ b1,
    const float* __restrict__ W2, const float* __restrict__ b2,
    float* __restrict__ H0) {
  // LDS union: phase-1 double-buffered A tiles (16 KB) overlap phase-B h1s.
  __shared__ __align__(16) char smem[46224];
  short* Abase = (short*)smem;                      // [2][4096] shorts: Ah@b*4096, Al@b*4096+2048
  unsigned short* h1s = (unsigned short*)smem;      // [64][264]
  float* W2s = (float*)(smem + 33792);              // [41][68]
  float* psum = (float*)(smem + 33792 + 11152);     // [64][4]
  float* rnorm = psum + 256;                        // [64]

  const int tid = threadIdx.x;
  const int lane = tid & 63;
  const int w = tid >> 6;
  const int r0 = blockIdx.x * 64;

  // A-staging: thread tid produces 16B chunk tid = row (tid>>6)*16+(tid&15),
  // k-slot ((tid>>4)&3)*8  (reader: chunk = mi*64 + lane)
  const int arow = ((tid >> 6) << 4) | (tid & 15);
  const int akoff = ((tid >> 4) & 3) << 3;
  const int gr_ld = r0 + arow;
  const bool rok = gr_ld < N_NODES;
  const float* xrow = x + (size_t)gr_ld * IN_C;

  // B fragment addressing (global, L2-resident)
  const int bcol0 = (w << 6) + (lane & 15);
  const int bko = (lane >> 4) << 3;

  f32x4 acc[4][4];
#pragma unroll
  for (int s = 0; s < 4; ++s) {
    float bv = b1[bcol0 + s * 16];
#pragma unroll
    for (int mi = 0; mi < 4; ++mi) acc[mi][s] = (f32x4){bv, bv, bv, bv};
  }

#define LOADX(T, V)                                                        \
  {                                                                        \
    int kb = (T) * 32 + akoff;                                             \
    if (rok && kb + 8 <= IN_C) {                                           \
      float2 p0 = *(const float2*)(xrow + kb);                             \
      float2 p1 = *(const float2*)(xrow + kb + 2);                         \
      float2 p2 = *(const float2*)(xrow + kb + 4);                         \
      float2 p3 = *(const float2*)(xrow + kb + 6);                         \
      V[0] = p0.x; V[1] = p0.y; V[2] = p1.x; V[3] = p1.y;                  \
      V[4] = p2.x; V[5] = p2.y; V[6] = p3.x; V[7] = p3.y;                  \
    } else {                                                               \
      _Pragma("unroll") for (int j = 0; j < 8; ++j) {                      \
        int k = kb + j;                                                    \
        V[j] = (rok && k < IN_C) ? xrow[k] : 0.f;                          \
      }                                                                    \
    }                                                                      \
  }

#define LOADB(T, BH, BL)                                                   \
  {                                                                        \
    int kgb = (T) * 32 + bko;                                              \
    _Pragma("unroll") for (int s = 0; s < 4; ++s) {                        \
      const int n = bcol0 + s * 16;                                        \
      BH[s] = *(const bf16x8*)(Wh + (size_t)n * KPAD + kgb);               \
      BL[s] = *(const bf16x8*)(Wl + (size_t)n * KPAD + kgb);               \
    }                                                                      \
  }

#define CVST(V, B)                                                         \
  {                                                                        \
    union { unsigned short u[8]; bf16x8 vec; } up, lp;                     \
    _Pragma("unroll") for (int j = 0; j < 8; ++j) {                        \
      unsigned short hi = f2bf(V[j]);                                      \
      up.u[j] = hi;                                                        \
      lp.u[j] = f2bf(V[j] - bf2f(hi));                                     \
    }                                                                      \
    *(bf16x8*)&Abase[(B) * 4096 + tid * 8] = up.vec;                       \
    *(bf16x8*)&Abase[(B) * 4096 + 2048 + tid * 8] = lp.vec;                \
  }

  // prologue: tile 0 staged, B(0) in regs
  float xv[8];
  LOADX(0, xv);
  bf16x8 bhv[4], blv[4];
  LOADB(0, bhv, blv);
  CVST(xv, 0);
  __syncthreads();

  for (int t = 0; t < NT; ++t) {
    const int cur = t & 1;
    const int tn = (t + 1 < NT) ? t + 1 : t;
    float xn[8];
    LOADX(tn, xn);                 // issue next x loads (hidden under MFMA)
    bf16x8 bhn[4], bln[4];
    LOADB(tn, bhn, bln);           // issue next B loads (L2)

    bf16x8 ah[4], al[4];
#pragma unroll
    for (int mi = 0; mi < 4; ++mi) {
      ah[mi] = *(const bf16x8*)&Abase[cur * 4096 + (mi * 64 + lane) * 8];
      al[mi] = *(const bf16x8*)&Abase[cur * 4096 + 2048 + (mi * 64 + lane) * 8];
    }
#pragma unroll
    for (int mi = 0; mi < 4; ++mi)
#pragma unroll
      for (int s = 0; s < 4; ++s) {
        acc[mi][s] = __builtin_amdgcn_mfma_f32_16x16x32_bf16(ah[mi], bhv[s], acc[mi][s], 0, 0, 0);
        acc[mi][s] = __builtin_amdgcn_mfma_f32_16x16x32_bf16(al[mi], bhv[s], acc[mi][s], 0, 0, 0);
        acc[mi][s] = __builtin_amdgcn_mfma_f32_16x16x32_bf16(ah[mi], blv[s], acc[mi][s], 0, 0, 0);
      }

    CVST(xn, cur ^ 1);             // stage next tile (duplicate on last, unread)
#pragma unroll
    for (int s = 0; s < 4; ++s) { bhv[s] = bhn[s]; blv[s] = bln[s]; }
    __syncthreads();               // single barrier per tile
  }

  // write relu(h1) as bf16 into LDS (C layout: row=(lane>>4)*4+q, col=lane&15)
#pragma unroll
  for (int mi = 0; mi < 4; ++mi)
#pragma unroll
    for (int s = 0; s < 4; ++s)
#pragma unroll
      for (int q = 0; q < 4; ++q) {
        int rr = mi * 16 + ((lane >> 4) << 2) + q;
        int cc = (w << 6) + s * 16 + (lane & 15);
        h1s[rr * 264 + cc] = f2bf(fmaxf(acc[mi][s][q], 0.f));
      }
  __syncthreads();

  // phase B: h2 = h1 @ W2^T + b2, then L2-normalize rows
  const int br = tid & 63;
  const int cg = w;
  const int nj = (cg == 0) ? 11 : 10;
  float outs[11];
#pragma unroll
  for (int j = 0; j < 11; ++j) {
    int c = cg + 4 * j;
    outs[j] = (c < OUTC) ? b2[c] : 0.f;
  }

  for (int kc = 0; kc < 4; ++kc) {
    for (int e = tid; e < OUTC * 64; e += 256) {
      int c = e >> 6, kk = e & 63;
      W2s[c * 68 + kk] = W2[c * HID_C + kc * 64 + kk];
    }
    __syncthreads();
#pragma unroll 4
    for (int kk = 0; kk < 64; kk += 4) {
      const ushort4 hv = *(const ushort4*)&h1s[br * 264 + kc * 64 + kk];
      float h0v = bf2f(hv.x), h1v = bf2f(hv.y), h2v = bf2f(hv.z), h3v = bf2f(hv.w);
      for (int j = 0; j < nj; ++j) {
        const float4 wv = *(const float4*)&W2s[(cg + 4 * j) * 68 + kk];
        outs[j] += h0v * wv.x + h1v * wv.y + h2v * wv.z + h3v * wv.w;
      }
    }
    __syncthreads();
  }

  float ss = 0.f;
  for (int j = 0; j < nj; ++j) ss += outs[j] * outs[j];
  psum[br * 4 + cg] = ss;
  __syncthreads();
  if (tid < 64) {
    float s = psum[tid * 4] + psum[tid * 4 + 1] + psum[tid * 4 + 2] + psum[tid * 4 + 3];
    rnorm[tid] = 1.f / fmaxf(sqrtf(s), 1e-12f);
  }
  __syncthreads();
  const int gr = r0 + br;
  if (gr < N_NODES) {
    float rn = rnorm[br];
    for (int j = 0; j < nj; ++j) H0[(size_t)gr * PADC + cg + 4 * j] = outs[j] * rn;
    if (cg == 3)
      for (int c = OUTC; c < PADC; ++c) H0[(size_t)gr * PADC + c] = 0.f;
  }
}

// ---------------- exclusive scan (3 kernels) ----------------
__global__ __launch_bounds__(256) void scan1_kernel(const unsigned* __restrict__ deg,
                                                    unsigned* __restrict__ offs,
                                                    unsigned* __restrict__ btot) {
  __shared__ unsigned wsum[4];
  __shared__ unsigned wbase[4];
  const int t = threadIdx.x, lane = t & 63, w = t >> 6;
  const int base = blockIdx.x * 1024 + t * 4;
  unsigned v[4];
#pragma unroll
  for (int i = 0; i < 4; ++i) {
    int idx = base + i;
    v[i] = (idx < N_NODES) ? deg[idx] : 0u;
  }
  unsigned tsum = v[0] + v[1] + v[2] + v[3];
  unsigned inc = tsum;
  for (int d = 1; d < 64; d <<= 1) {
    unsigned n = (unsigned)__shfl_up((int)inc, d);
    if (lane >= d) inc += n;
  }
  if (lane == 63) wsum[w] = inc;
  __syncthreads();
  if (t == 0) {
    unsigned run = 0;
    for (int i = 0; i < 4; ++i) { unsigned s = wsum[i]; wbase[i] = run; run += s; }
    btot[blockIdx.x] = run;
  }
  __syncthreads();
  unsigned ex = wbase[w] + inc - tsum;
#pragma unroll
  for (int i = 0; i < 4; ++i) {
    int idx = base + i;
    if (idx < N_NODES) offs[idx] = ex;
    ex += v[i];
  }
}

__global__ __launch_bounds__(128) void scan2_kernel(const unsigned* __restrict__ btot,
                                                    unsigned* __restrict__ bbase, int B) {
  __shared__ unsigned wsum[2];
  __shared__ unsigned wbase[2];
  const int t = threadIdx.x, lane = t & 63, w = t >> 6;
  unsigned v = (t < B) ? btot[t] : 0u;
  unsigned inc = v;
  for (int d = 1; d < 64; d <<= 1) {
    unsigned n = (unsigned)__shfl_up((int)inc, d);
    if (lane >= d) inc += n;
  }
  if (lane == 63) wsum[w] = inc;
  __syncthreads();
  if (t == 0) {
    unsigned run = 0;
    for (int i = 0; i < 2; ++i) { unsigned s = wsum[i]; wbase[i] = run; run += s; }
  }
  __syncthreads();
  unsigned ex = wbase[w] + inc - v;
  if (t < B) bbase[t] = ex;
}

__global__ __launch_bounds__(256) void scan3_kernel(unsigned* __restrict__ offs,
                                                    const unsigned* __restrict__ bbase) {
  int i = blockIdx.x * 256 + threadIdx.x;
  if (i < N_NODES) offs[i] += bbase[i >> 10];
}

// ---------------- CSC scatter ----------------
__global__ __launch_bounds__(256) void scatter_kernel(const int* __restrict__ row,
                                                      const int* __restrict__ col,
                                                      const float* __restrict__ dinv,
                                                      const unsigned* __restrict__ offs,
                                                      unsigned* __restrict__ cursor,
                                                      int2* __restrict__ rec) {
  int e = blockIdx.x * 256 + threadIdx.x;
  if (e >= N_EDGES) return;
  int r = row[e], c = col[e];
  float wgt = dinv[r] * dinv[c];
  unsigned pos = offs[c] + atomicAdd(&cursor[c], 1u);
  rec[pos] = make_int2(r, __float_as_int(wgt));
}

// ---------------- APPNP iteration (gather, padded rows, unroll 8) --------
__global__ __launch_bounds__(256) void prop_kernel(const float* __restrict__ hsrc,
                                                   const float* __restrict__ h0,
                                                   float* __restrict__ hdst,
                                                   const int dstride,
                                                   const int2* __restrict__ rec,
                                                   const unsigned* __restrict__ offs,
                                                   const unsigned* __restrict__ deg,
                                                   const float* __restrict__ dinv) {
  const int w = threadIdx.x >> 6;
  const int lane = threadIdx.x & 63;
  const int n = blockIdx.x * 4 + w;
  if (n >= N_NODES) return;
  const unsigned s = offs[n];
  const unsigned e = s + deg[n];
  if (lane < PADC) {
    float acc0 = 0.f, acc1 = 0.f;
    unsigned i = s;
    for (; i + 8 <= e; i += 8) {
      int2 q0 = rec[i],     q1 = rec[i + 1], q2 = rec[i + 2], q3 = rec[i + 3];
      int2 q4 = rec[i + 4], q5 = rec[i + 5], q6 = rec[i + 6], q7 = rec[i + 7];
      float a0 = hsrc[(size_t)q0.x * PADC + lane];
      float a1 = hsrc[(size_t)q1.x * PADC + lane];
      float a2 = hsrc[(size_t)q2.x * PADC + lane];
      float a3 = hsrc[(size_t)q3.x * PADC + lane];
      float a4 = hsrc[(size_t)q4.x * PADC + lane];
      float a5 = hsrc[(size_t)q5.x * PADC + lane];
      float a6 = hsrc[(size_t)q6.x * PADC + lane];
      float a7 = hsrc[(size_t)q7.x * PADC + lane];
      acc0 += a0 * __int_as_float(q0.y); acc1 += a1 * __int_as_float(q1.y);
      acc0 += a2 * __int_as_float(q2.y); acc1 += a3 * __int_as_float(q3.y);
      acc0 += a4 * __int_as_float(q4.y); acc1 += a5 * __int_as_float(q5.y);
      acc0 += a6 * __int_as_float(q6.y); acc1 += a7 * __int_as_float(q7.y);
    }
    for (; i < e; ++i) {
      int2 q = rec[i];
      acc0 += hsrc[(size_t)q.x * PADC + lane] * __int_as_float(q.y);
    }
    float di = dinv[n];
    acc0 += hsrc[(size_t)n * PADC + lane] * di * di;  // self-loop
    float o = 0.9f * (acc0 + acc1) + 0.1f * h0[(size_t)n * PADC + lane];
    if (dstride == PADC) hdst[(size_t)n * PADC + lane] = o;
    else if (lane < OUTC) hdst[(size_t)n * OUTC + lane] = o;
  }
}

// ---------------- host ----------------
extern "C" void kernel_launch(void* const* d_in, const int* in_sizes, int n_in,
                              void* d_out, int out_size, void* d_ws, size_t ws_size,
                              hipStream_t stream) {
  const float* x  = (const float*)d_in[0];
  const int*   ei = (const int*)d_in[1];
  const float* W1 = (const float*)d_in[2];
  const float* b1 = (const float*)d_in[3];
  const float* W2 = (const float*)d_in[4];
  const float* b2 = (const float*)d_in[5];
  float* out = (float*)d_out;

  char* p = (char*)d_ws;
  auto alloc = [&](size_t bytes) {
    char* q = p;
    p += (bytes + 255) & ~(size_t)255;
    return q;
  };
  unsigned* deg    = (unsigned*)alloc((size_t)N_NODES * 4);
  float*    dinv   = (float*)   alloc((size_t)N_NODES * 4);
  unsigned* offs   = (unsigned*)alloc((size_t)N_NODES * 4);
  unsigned* btot   = (unsigned*)alloc(128 * 4);
  unsigned* bbase  = (unsigned*)alloc(128 * 4);
  unsigned* cursor = (unsigned*)alloc((size_t)N_NODES * 4);
  int2*     rec    = (int2*)    alloc((size_t)N_EDGES * 8);
  float*    H0     = (float*)   alloc((size_t)N_NODES * PADC * 4);
  float*    HA     = (float*)   alloc((size_t)N_NODES * PADC * 4);
  float*    HB     = (float*)   alloc((size_t)N_NODES * PADC * 4);
  unsigned short* Wh = (unsigned short*)alloc((size_t)HID_C * KPAD * 2);
  unsigned short* Wl = (unsigned short*)alloc((size_t)HID_C * KPAD * 2);

  const int* row = ei;            // edge_index[0] : sources
  const int* col = ei + N_EDGES;  // edge_index[1] : targets

  hipMemsetAsync(deg, 0, (size_t)N_NODES * 4, stream);
  hipMemsetAsync(cursor, 0, (size_t)N_NODES * 4, stream);

  deg_kernel<<<(N_EDGES + 255) / 256, 256, 0, stream>>>(col, deg);
  dinv_kernel<<<(N_NODES + 255) / 256, 256, 0, stream>>>(deg, dinv);
  wprep_kernel<<<(HID_C * KPAD + 255) / 256, 256, 0, stream>>>(W1, Wh, Wl);
  mlp_kernel<<<(N_NODES + 63) / 64, 256, 0, stream>>>(x, Wh, Wl, b1, W2, b2, H0);

  const int B = (N_NODES + 1023) / 1024;  // 98
  scan1_kernel<<<B, 256, 0, stream>>>(deg, offs, btot);
  scan2_kernel<<<1, 128, 0, stream>>>(btot, bbase, B);
  scan3_kernel<<<(N_NODES + 255) / 256, 256, 0, stream>>>(offs, bbase);
  scatter_kernel<<<(N_EDGES + 255) / 256, 256, 0, stream>>>(row, col, dinv, offs, cursor, rec);

  const float* src = H0;
  float* bufs[2] = {HA, HB};
  for (int k = 0; k < K_ITERS; ++k) {
    float* dst;
    int ds;
    if (k == K_ITERS - 1) { dst = out; ds = OUTC; }
    else                  { dst = bufs[k & 1]; ds = PADC; }
    prop_kernel<<<(N_NODES + 3) / 4, 256, 0, stream>>>(src, H0, dst, ds, rec, offs, deg, dinv);
    src = dst;
  }
}

// Round 4
// 1935.725 us; speedup vs baseline: 1.9924x; 1.0021x over previous
//
#include <hip/hip_runtime.h>

#define N_NODES 100000
#define N_EDGES 3200000
#define IN_C 602
#define KPAD 608
#define NT (KPAD / 32)  // 19
#define HID_C 256
#define OUTC 41
#define HSTR 64   // bf16 h row stride (128 B = 2 cache lines)
#define K_ITERS 10

typedef __attribute__((ext_vector_type(8))) short bf16x8;
typedef __attribute__((ext_vector_type(4))) float f32x4;

static __device__ __forceinline__ unsigned short f2bf(float f) {
  unsigned u = __float_as_uint(f);
  u += 0x7fffu + ((u >> 16) & 1u);
  return (unsigned short)(u >> 16);
}
static __device__ __forceinline__ float bf2f(unsigned short h) {
  return __uint_as_float(((unsigned)h) << 16);
}

// ---------------- degree ----------------
__global__ __launch_bounds__(256) void deg_kernel(const int* __restrict__ col,
                                                  unsigned* __restrict__ deg) {
  int e = blockIdx.x * 256 + threadIdx.x;
  if (e < N_EDGES) atomicAdd(&deg[col[e]], 1u);
}

__global__ __launch_bounds__(256) void dinv_kernel(const unsigned* __restrict__ deg,
                                                   float* __restrict__ dinv) {
  int i = blockIdx.x * 256 + threadIdx.x;
  if (i < N_NODES) dinv[i] = rsqrtf((float)(deg[i] + 1u));
}

// ---------------- W1 bf16 hi/lo split (one-time, 623 KB) ----------------
__global__ __launch_bounds__(256) void wprep_kernel(const float* __restrict__ W1,
                                                    unsigned short* __restrict__ Wh,
                                                    unsigned short* __restrict__ Wl) {
  int idx = blockIdx.x * 256 + threadIdx.x;
  if (idx >= HID_C * KPAD) return;
  int n = idx / KPAD, k = idx % KPAD;
  float v = (k < IN_C) ? W1[n * IN_C + k] : 0.f;
  unsigned short hi = f2bf(v);
  Wh[idx] = hi;
  Wl[idx] = f2bf(v - bf2f(hi));
}

// ---------------- fused MLP: barrier-free MFMA GEMM1 + fp32 GEMM2 --------
// GEMM1: x (bf16-rounded in-reg) @ [Wh+Wl]^T, no LDS, no barriers.
// Each wave: 64 rows x 64 cols; A fragments loaded straight from row-major x.
__global__ __launch_bounds__(256, 2) void mlp_kernel(
    const float* __restrict__ x,
    const unsigned short* __restrict__ Wh, const unsigned short* __restrict__ Wl,
    const float* __restrict__ b1,
    const float* __restrict__ W2, const float* __restrict__ b2,
    unsigned short* __restrict__ H0) {
  __shared__ __align__(16) char smem[46224];
  unsigned short* h1s = (unsigned short*)smem;        // [64][264]
  float* W2s = (float*)(smem + 33792);                // [41][68]
  float* psum = (float*)(smem + 33792 + 11152);       // [64][4]
  float* rnorm = psum + 256;                          // [64]

  const int tid = threadIdx.x;
  const int lane = tid & 63;
  const int w = tid >> 6;
  const int r0 = blockIdx.x * 64;

  const int akoff = (lane >> 4) << 3;  // k-offset within 32-tile
  const int fr = lane & 15;            // fragment row / col within 16

  // A row pointers (clamped; garbage rows discarded at store)
  const float* xr[4];
#pragma unroll
  for (int mi = 0; mi < 4; ++mi) {
    int gr = r0 + mi * 16 + fr;
    if (gr >= N_NODES) gr = N_NODES - 1;
    xr[mi] = x + (size_t)gr * IN_C;
  }

  // B addressing (L2-resident Wh/Wl)
  const int bcol0 = (w << 6) + fr;

  f32x4 acc[4][4];
#pragma unroll
  for (int s = 0; s < 4; ++s) {
    float bv = b1[bcol0 + s * 16];
#pragma unroll
    for (int mi = 0; mi < 4; ++mi) acc[mi][s] = (f32x4){bv, bv, bv, bv};
  }

#define LOADA(T, FA)                                                      \
  { const int kb = (T) * 32 + akoff;                                      \
    if (kb + 8 <= IN_C) {                                                 \
      _Pragma("unroll") for (int mi = 0; mi < 4; ++mi) {                  \
        const float* pp = xr[mi] + kb;                                    \
        float2 p0 = *(const float2*)(pp);                                 \
        float2 p1 = *(const float2*)(pp + 2);                             \
        float2 p2 = *(const float2*)(pp + 4);                             \
        float2 p3 = *(const float2*)(pp + 6);                             \
        FA[mi][0] = p0.x; FA[mi][1] = p0.y;                               \
        FA[mi][2] = p1.x; FA[mi][3] = p1.y;                               \
        FA[mi][4] = p2.x; FA[mi][5] = p2.y;                               \
        FA[mi][6] = p3.x; FA[mi][7] = p3.y;                               \
      }                                                                   \
    } else {                                                              \
      _Pragma("unroll") for (int mi = 0; mi < 4; ++mi) {                  \
        const float* pp = xr[mi] + kb;                                    \
        float2 p0 = *(const float2*)(pp);                                 \
        FA[mi][0] = p0.x; FA[mi][1] = p0.y;                               \
        _Pragma("unroll") for (int j = 2; j < 8; ++j) FA[mi][j] = 0.f;    \
      }                                                                   \
    } }

#define LOADB(T, BH, BL)                                                  \
  { const int kgb = (T) * 32 + akoff;                                     \
    _Pragma("unroll") for (int s = 0; s < 4; ++s) {                       \
      const int n = bcol0 + s * 16;                                       \
      BH[s] = *(const bf16x8*)(Wh + (size_t)n * KPAD + kgb);              \
      BL[s] = *(const bf16x8*)(Wl + (size_t)n * KPAD + kgb);              \
    } }

#define CVTA(FA, AH)                                                      \
  { _Pragma("unroll") for (int mi = 0; mi < 4; ++mi) {                    \
      union { unsigned u[4]; bf16x8 v; } tt;                              \
      _Pragma("unroll") for (int jj = 0; jj < 4; ++jj)                    \
        asm("v_cvt_pk_bf16_f32 %0, %1, %2"                                \
            : "=v"(tt.u[jj])                                              \
            : "v"(FA[mi][2 * jj]), "v"(FA[mi][2 * jj + 1]));              \
      AH[mi] = tt.v; } }

#define MFMAS(AH, BH, BL)                                                 \
  { _Pragma("unroll") for (int mi = 0; mi < 4; ++mi)                      \
      _Pragma("unroll") for (int s = 0; s < 4; ++s) {                     \
        acc[mi][s] = __builtin_amdgcn_mfma_f32_16x16x32_bf16(             \
            AH[mi], BH[s], acc[mi][s], 0, 0, 0);                          \
        acc[mi][s] = __builtin_amdgcn_mfma_f32_16x16x32_bf16(             \
            AH[mi], BL[s], acc[mi][s], 0, 0, 0);                          \
      } }

  float fA[4][8], fB[4][8];
  bf16x8 bhA[4], blA[4], bhB[4], blB[4], ah[4];
  LOADA(0, fA);
  LOADB(0, bhA, blA);
  int t = 0;
  for (; t + 2 <= NT; t += 2) {
    LOADA(t + 1, fB);
    LOADB(t + 1, bhB, blB);
    CVTA(fA, ah);
    MFMAS(ah, bhA, blA);
    if (t + 2 < NT) {
      LOADA(t + 2, fA);
      LOADB(t + 2, bhA, blA);
    }
    CVTA(fB, ah);
    MFMAS(ah, bhB, blB);
  }
  if (t < NT) {  // NT odd: final tile
    CVTA(fA, ah);
    MFMAS(ah, bhA, blA);
  }

  // write relu(h1) as bf16 into LDS (C layout: row=(lane>>4)*4+q, col=lane&15)
#pragma unroll
  for (int mi = 0; mi < 4; ++mi)
#pragma unroll
    for (int s = 0; s < 4; ++s)
#pragma unroll
      for (int q = 0; q < 4; ++q) {
        int rr = mi * 16 + ((lane >> 4) << 2) + q;
        int cc = (w << 6) + s * 16 + fr;
        h1s[rr * 264 + cc] = f2bf(fmaxf(acc[mi][s][q], 0.f));
      }
  __syncthreads();

  // phase B: h2 = h1 @ W2^T + b2, then L2-normalize rows, store bf16
  const int br = tid & 63;
  const int cg = w;
  const int nj = (cg == 0) ? 11 : 10;
  float outs[11];
#pragma unroll
  for (int j = 0; j < 11; ++j) {
    int c = cg + 4 * j;
    outs[j] = (c < OUTC) ? b2[c] : 0.f;
  }

  for (int kc = 0; kc < 4; ++kc) {
    for (int e = tid; e < OUTC * 64; e += 256) {
      int c = e >> 6, kk = e & 63;
      W2s[c * 68 + kk] = W2[c * HID_C + kc * 64 + kk];
    }
    __syncthreads();
#pragma unroll 4
    for (int kk = 0; kk < 64; kk += 4) {
      const ushort4 hv = *(const ushort4*)&h1s[br * 264 + kc * 64 + kk];
      float h0v = bf2f(hv.x), h1v = bf2f(hv.y), h2v = bf2f(hv.z), h3v = bf2f(hv.w);
      for (int j = 0; j < nj; ++j) {
        const float4 wv = *(const float4*)&W2s[(cg + 4 * j) * 68 + kk];
        outs[j] += h0v * wv.x + h1v * wv.y + h2v * wv.z + h3v * wv.w;
      }
    }
    __syncthreads();
  }

  float ss = 0.f;
  for (int j = 0; j < nj; ++j) ss += outs[j] * outs[j];
  psum[br * 4 + cg] = ss;
  __syncthreads();
  if (tid < 64) {
    float s = psum[tid * 4] + psum[tid * 4 + 1] + psum[tid * 4 + 2] + psum[tid * 4 + 3];
    rnorm[tid] = 1.f / fmaxf(sqrtf(s), 1e-12f);
  }
  __syncthreads();
  const int gr = r0 + br;
  if (gr < N_NODES) {
    float rn = rnorm[br];
#pragma unroll
    for (int j = 0; j < 16; ++j) {
      int c = cg + 4 * j;  // covers 0..63 across the 4 col-groups
      float val = (j < nj) ? outs[j] * rn : 0.f;
      H0[(size_t)gr * HSTR + c] = f2bf(val);
    }
  }
}

// ---------------- exclusive scan (3 kernels) ----------------
__global__ __launch_bounds__(256) void scan1_kernel(const unsigned* __restrict__ deg,
                                                    unsigned* __restrict__ offs,
                                                    unsigned* __restrict__ btot) {
  __shared__ unsigned wsum[4];
  __shared__ unsigned wbase[4];
  const int t = threadIdx.x, lane = t & 63, w = t >> 6;
  const int base = blockIdx.x * 1024 + t * 4;
  unsigned v[4];
#pragma unroll
  for (int i = 0; i < 4; ++i) {
    int idx = base + i;
    v[i] = (idx < N_NODES) ? deg[idx] : 0u;
  }
  unsigned tsum = v[0] + v[1] + v[2] + v[3];
  unsigned inc = tsum;
  for (int d = 1; d < 64; d <<= 1) {
    unsigned n = (unsigned)__shfl_up((int)inc, d);
    if (lane >= d) inc += n;
  }
  if (lane == 63) wsum[w] = inc;
  __syncthreads();
  if (t == 0) {
    unsigned run = 0;
    for (int i = 0; i < 4; ++i) { unsigned s = wsum[i]; wbase[i] = run; run += s; }
    btot[blockIdx.x] = run;
  }
  __syncthreads();
  unsigned ex = wbase[w] + inc - tsum;
#pragma unroll
  for (int i = 0; i < 4; ++i) {
    int idx = base + i;
    if (idx < N_NODES) offs[idx] = ex;
    ex += v[i];
  }
}

__global__ __launch_bounds__(128) void scan2_kernel(const unsigned* __restrict__ btot,
                                                    unsigned* __restrict__ bbase, int B) {
  __shared__ unsigned wsum[2];
  __shared__ unsigned wbase[2];
  const int t = threadIdx.x, lane = t & 63, w = t >> 6;
  unsigned v = (t < B) ? btot[t] : 0u;
  unsigned inc = v;
  for (int d = 1; d < 64; d <<= 1) {
    unsigned n = (unsigned)__shfl_up((int)inc, d);
    if (lane >= d) inc += n;
  }
  if (lane == 63) wsum[w] = inc;
  __syncthreads();
  if (t == 0) {
    unsigned run = 0;
    for (int i = 0; i < 2; ++i) { unsigned s = wsum[i]; wbase[i] = run; run += s; }
  }
  __syncthreads();
  unsigned ex = wbase[w] + inc - v;
  if (t < B) bbase[t] = ex;
}

__global__ __launch_bounds__(256) void scan3_kernel(unsigned* __restrict__ offs,
                                                    const unsigned* __restrict__ bbase) {
  int i = blockIdx.x * 256 + threadIdx.x;
  if (i < N_NODES) offs[i] += bbase[i >> 10];
}

// ---------------- CSC scatter ----------------
__global__ __launch_bounds__(256) void scatter_kernel(const int* __restrict__ row,
                                                      const int* __restrict__ col,
                                                      const float* __restrict__ dinv,
                                                      const unsigned* __restrict__ offs,
                                                      unsigned* __restrict__ cursor,
                                                      int2* __restrict__ rec) {
  int e = blockIdx.x * 256 + threadIdx.x;
  if (e >= N_EDGES) return;
  int r = row[e], c = col[e];
  float wgt = dinv[r] * dinv[c];
  unsigned pos = offs[c] + atomicAdd(&cursor[c], 1u);
  rec[pos] = make_int2(r, __float_as_int(wgt));
}

// ---------------- APPNP iteration (bf16 gather, 128 B rows) --------------
__global__ __launch_bounds__(256) void prop_kernel(
    const unsigned short* __restrict__ hsrc,
    const unsigned short* __restrict__ h0,
    unsigned short* __restrict__ hdst,   // used when fout == nullptr
    float* __restrict__ fout,            // non-null on last iteration
    const int2* __restrict__ rec,
    const unsigned* __restrict__ offs,
    const unsigned* __restrict__ deg,
    const float* __restrict__ dinv) {
  const int w = threadIdx.x >> 6;
  const int lane = threadIdx.x & 63;
  const int n = blockIdx.x * 4 + w;
  if (n >= N_NODES) return;
  const unsigned s = offs[n];
  const unsigned e = s + deg[n];
  float acc0 = 0.f, acc1 = 0.f;
  unsigned i = s;
  for (; i + 8 <= e; i += 8) {
    int2 q0 = rec[i],     q1 = rec[i + 1], q2 = rec[i + 2], q3 = rec[i + 3];
    int2 q4 = rec[i + 4], q5 = rec[i + 5], q6 = rec[i + 6], q7 = rec[i + 7];
    float a0 = bf2f(hsrc[(size_t)q0.x * HSTR + lane]);
    float a1 = bf2f(hsrc[(size_t)q1.x * HSTR + lane]);
    float a2 = bf2f(hsrc[(size_t)q2.x * HSTR + lane]);
    float a3 = bf2f(hsrc[(size_t)q3.x * HSTR + lane]);
    float a4 = bf2f(hsrc[(size_t)q4.x * HSTR + lane]);
    float a5 = bf2f(hsrc[(size_t)q5.x * HSTR + lane]);
    float a6 = bf2f(hsrc[(size_t)q6.x * HSTR + lane]);
    float a7 = bf2f(hsrc[(size_t)q7.x * HSTR + lane]);
    acc0 += a0 * __int_as_float(q0.y); acc1 += a1 * __int_as_float(q1.y);
    acc0 += a2 * __int_as_float(q2.y); acc1 += a3 * __int_as_float(q3.y);
    acc0 += a4 * __int_as_float(q4.y); acc1 += a5 * __int_as_float(q5.y);
    acc0 += a6 * __int_as_float(q6.y); acc1 += a7 * __int_as_float(q7.y);
  }
  for (; i < e; ++i) {
    int2 q = rec[i];
    acc0 += bf2f(hsrc[(size_t)q.x * HSTR + lane]) * __int_as_float(q.y);
  }
  float di = dinv[n];
  acc0 += bf2f(hsrc[(size_t)n * HSTR + lane]) * di * di;  // self-loop
  float o = 0.9f * (acc0 + acc1) + 0.1f * bf2f(h0[(size_t)n * HSTR + lane]);
  if (fout) {
    if (lane < OUTC) fout[(size_t)n * OUTC + lane] = o;
  } else {
    hdst[(size_t)n * HSTR + lane] = f2bf(o);
  }
}

// ---------------- host ----------------
extern "C" void kernel_launch(void* const* d_in, const int* in_sizes, int n_in,
                              void* d_out, int out_size, void* d_ws, size_t ws_size,
                              hipStream_t stream) {
  const float* x  = (const float*)d_in[0];
  const int*   ei = (const int*)d_in[1];
  const float* W1 = (const float*)d_in[2];
  const float* b1 = (const float*)d_in[3];
  const float* W2 = (const float*)d_in[4];
  const float* b2 = (const float*)d_in[5];
  float* out = (float*)d_out;

  char* p = (char*)d_ws;
  auto alloc = [&](size_t bytes) {
    char* q = p;
    p += (bytes + 255) & ~(size_t)255;
    return q;
  };
  unsigned* deg    = (unsigned*)alloc((size_t)N_NODES * 4);
  float*    dinv   = (float*)   alloc((size_t)N_NODES * 4);
  unsigned* offs   = (unsigned*)alloc((size_t)N_NODES * 4);
  unsigned* btot   = (unsigned*)alloc(128 * 4);
  unsigned* bbase  = (unsigned*)alloc(128 * 4);
  unsigned* cursor = (unsigned*)alloc((size_t)N_NODES * 4);
  int2*     rec    = (int2*)    alloc((size_t)N_EDGES * 8);
  unsigned short* H0 = (unsigned short*)alloc((size_t)N_NODES * HSTR * 2);
  unsigned short* HA = (unsigned short*)alloc((size_t)N_NODES * HSTR * 2);
  unsigned short* HB = (unsigned short*)alloc((size_t)N_NODES * HSTR * 2);
  unsigned short* Wh = (unsigned short*)alloc((size_t)HID_C * KPAD * 2);
  unsigned short* Wl = (unsigned short*)alloc((size_t)HID_C * KPAD * 2);

  const int* row = ei;            // edge_index[0] : sources
  const int* col = ei + N_EDGES;  // edge_index[1] : targets

  hipMemsetAsync(deg, 0, (size_t)N_NODES * 4, stream);
  hipMemsetAsync(cursor, 0, (size_t)N_NODES * 4, stream);

  deg_kernel<<<(N_EDGES + 255) / 256, 256, 0, stream>>>(col, deg);
  dinv_kernel<<<(N_NODES + 255) / 256, 256, 0, stream>>>(deg, dinv);
  wprep_kernel<<<(HID_C * KPAD + 255) / 256, 256, 0, stream>>>(W1, Wh, Wl);
  mlp_kernel<<<(N_NODES + 63) / 64, 256, 0, stream>>>(x, Wh, Wl, b1, W2, b2, H0);

  const int B = (N_NODES + 1023) / 1024;  // 98
  scan1_kernel<<<B, 256, 0, stream>>>(deg, offs, btot);
  scan2_kernel<<<1, 128, 0, stream>>>(btot, bbase, B);
  scan3_kernel<<<(N_NODES + 255) / 256, 256, 0, stream>>>(offs, bbase);
  scatter_kernel<<<(N_EDGES + 255) / 256, 256, 0, stream>>>(row, col, dinv, offs, cursor, rec);

  const unsigned short* src = H0;
  unsigned short* bufs[2] = {HA, HB};
  for (int k = 0; k < K_ITERS; ++k) {
    bool last = (k == K_ITERS - 1);
    unsigned short* dst = last ? nullptr : bufs[k & 1];
    float* fdst = last ? out : nullptr;
    prop_kernel<<<(N_NODES + 3) / 4, 256, 0, stream>>>(src, H0, dst, fdst, rec, offs, deg, dinv);
    src = dst;
  }
}

// Round 5
// 1402.751 us; speedup vs baseline: 2.7494x; 1.3799x over previous
//
#include <hip/hip_runtime.h>

#define N_NODES 100000
#define N_EDGES 3200000
#define IN_C 602
#define KPAD 608
#define NT 19           // KPAD/32 k-tiles
#define HID_C 256
#define OUTC 41
#define HSTR 64         // bf16 h row stride (128 B = 2 cache lines)
#define K_ITERS 10

typedef __attribute__((ext_vector_type(8))) short bf16x8;
typedef __attribute__((ext_vector_type(4))) float f32x4;

static __device__ __forceinline__ unsigned short f2bf(float f) {
  unsigned u = __float_as_uint(f);
  u += 0x7fffu + ((u >> 16) & 1u);
  return (unsigned short)(u >> 16);
}
static __device__ __forceinline__ float bf2f(unsigned short h) {
  return __uint_as_float(((unsigned)h) << 16);
}
static __device__ __forceinline__ float bflo(unsigned u) {
  return __uint_as_float(u << 16);
}
static __device__ __forceinline__ float bfhi(unsigned u) {
  return __uint_as_float(u & 0xffff0000u);
}

// ---------------- degree ----------------
__global__ __launch_bounds__(256) void deg_kernel(const int* __restrict__ col,
                                                  unsigned* __restrict__ deg) {
  int e = blockIdx.x * 256 + threadIdx.x;
  if (e < N_EDGES) atomicAdd(&deg[col[e]], 1u);
}

__global__ __launch_bounds__(256) void dinv_kernel(const unsigned* __restrict__ deg,
                                                   float* __restrict__ dinv) {
  int i = blockIdx.x * 256 + threadIdx.x;
  if (i < N_NODES) dinv[i] = rsqrtf((float)(deg[i] + 1u));
}

// ------- W1 bf16 hi/lo split into FRAGMENT-LINEAR layout (one-time) -------
// Layout: [t][n][g][8] shorts, t=k-tile, n=output col, g=k-slot (lane>>4).
// A wave's B-fragment load (fixed t,s,w) is then one contiguous 1 KB read.
__global__ __launch_bounds__(256) void wprep_kernel(const float* __restrict__ W1,
                                                    unsigned short* __restrict__ Whf,
                                                    unsigned short* __restrict__ Wlf) {
  int idx = blockIdx.x * 256 + threadIdx.x;
  if (idx >= HID_C * KPAD) return;
  int n = idx / KPAD, k = idx % KPAD;
  float v = (k < IN_C) ? W1[n * IN_C + k] : 0.f;
  unsigned short hi = f2bf(v);
  int t = k >> 5, g = (k >> 3) & 3, j = k & 7;
  size_t dst = (size_t)t * 8192 + ((n << 2) + g) * 8 + j;
  Whf[dst] = hi;
  Wlf[dst] = f2bf(v - bf2f(hi));
}

// ---------------- fused MLP: coalesced MFMA GEMM1 + fp32 GEMM2 -----------
__global__ __launch_bounds__(256, 2) void mlp_kernel(
    const float* __restrict__ x,
    const unsigned short* __restrict__ Whf, const unsigned short* __restrict__ Wlf,
    const float* __restrict__ b1,
    const float* __restrict__ W2, const float* __restrict__ b2,
    unsigned short* __restrict__ H0) {
  __shared__ __align__(16) char smem[46224];
  float4* xt = (float4*)smem;                         // [2][512] float4: x dbuf, swizzled
  unsigned short* h1s = (unsigned short*)smem;        // [64][264] (phase B, after barrier)
  float* W2s = (float*)(smem + 33792);                // [41][68]
  float* psum = (float*)(smem + 33792 + 11152);       // [64][4]
  float* rnorm = psum + 256;                          // [64]

  const int tid = threadIdx.x;
  const int lane = tid & 63;
  const int w = tid >> 6;
  const int r0 = blockIdx.x * 64;

  const int fr = lane & 15;
  const int g = lane >> 4;             // k-slot

  // staging geometry: thread -> (row0, c0) and (row0+32, c0), block-linear
  const int srow = tid >> 3;           // 0..31
  const int sc = tid & 7;              // chunk 0..7 (16B units)
  int gr0 = r0 + srow;       if (gr0 >= N_NODES) gr0 = N_NODES - 1;
  int gr1 = r0 + srow + 32;  if (gr1 >= N_NODES) gr1 = N_NODES - 1;
  const float* xp0 = x + (size_t)gr0 * IN_C;
  const float* xp1 = x + (size_t)gr1 * IN_C;
  // swizzled LDS slots (16B units)
  const int ws0 = srow * 8 + (sc ^ (srow & 7));
  const int ws1 = (srow + 32) * 8 + (sc ^ (srow & 7));

  f32x4 acc[4][4];
  {
    const int bcol0 = (w << 6) + fr;
#pragma unroll
    for (int s = 0; s < 4; ++s) {
      float bv = b1[bcol0 + s * 16];
#pragma unroll
      for (int mi = 0; mi < 4; ++mi) acc[mi][s] = (f32x4){bv, bv, bv, bv};
    }
  }

  float4 sA, sB;
#define STAGE_LOAD(T)                                                      \
  { const int kb = (T) * 32 + sc * 4;                                      \
    if ((T) < NT - 1) {                                                    \
      sA = *(const float4*)(xp0 + kb);                                     \
      sB = *(const float4*)(xp1 + kb);                                     \
    } else {                                                               \
      float tmp0[4], tmp1[4];                                              \
      _Pragma("unroll") for (int j = 0; j < 4; ++j) {                      \
        int k = kb + j;                                                    \
        tmp0[j] = (k < IN_C) ? xp0[k] : 0.f;                               \
        tmp1[j] = (k < IN_C) ? xp1[k] : 0.f;                               \
      }                                                                    \
      sA = (float4){tmp0[0], tmp0[1], tmp0[2], tmp0[3]};                   \
      sB = (float4){tmp1[0], tmp1[1], tmp1[2], tmp1[3]};                   \
    } }

#define STAGE_WRITE(BUF)                                                   \
  { xt[(BUF) * 512 + ws0] = sA;                                            \
    xt[(BUF) * 512 + ws1] = sB; }

#define LOADB(T, BH, BL)                                                   \
  { const size_t tb = (size_t)(T) * 8192;                                  \
    _Pragma("unroll") for (int s = 0; s < 4; ++s) {                        \
      const int n4 = (((w << 6) + s * 16 + fr) << 2) + g;                  \
      BH[s] = *(const bf16x8*)(Whf + tb + n4 * 8);                         \
      BL[s] = *(const bf16x8*)(Wlf + tb + n4 * 8);                         \
    } }

  // frag read from swizzled LDS + cvt to bf16
#define READ_FRAGS(BUF, AH)                                                \
  { _Pragma("unroll") for (int mi = 0; mi < 4; ++mi) {                     \
      const int rr = mi * 16 + fr;                                         \
      float4 pa = xt[(BUF) * 512 + rr * 8 + ((2 * g) ^ (fr & 7))];         \
      float4 pb = xt[(BUF) * 512 + rr * 8 + ((2 * g + 1) ^ (fr & 7))];     \
      union { unsigned u[4]; bf16x8 v; } tt;                               \
      asm("v_cvt_pk_bf16_f32 %0, %1, %2" : "=v"(tt.u[0]) : "v"(pa.x), "v"(pa.y)); \
      asm("v_cvt_pk_bf16_f32 %0, %1, %2" : "=v"(tt.u[1]) : "v"(pa.z), "v"(pa.w)); \
      asm("v_cvt_pk_bf16_f32 %0, %1, %2" : "=v"(tt.u[2]) : "v"(pb.x), "v"(pb.y)); \
      asm("v_cvt_pk_bf16_f32 %0, %1, %2" : "=v"(tt.u[3]) : "v"(pb.z), "v"(pb.w)); \
      AH[mi] = tt.v; } }

#define MFMAS(AH, BH, BL)                                                  \
  { _Pragma("unroll") for (int mi = 0; mi < 4; ++mi)                       \
      _Pragma("unroll") for (int s = 0; s < 4; ++s) {                      \
        acc[mi][s] = __builtin_amdgcn_mfma_f32_16x16x32_bf16(              \
            AH[mi], BH[s], acc[mi][s], 0, 0, 0);                           \
        acc[mi][s] = __builtin_amdgcn_mfma_f32_16x16x32_bf16(              \
            AH[mi], BL[s], acc[mi][s], 0, 0, 0);                           \
      } }

  // prologue: tile0 in LDS, tile1 in regs, B(0) in regs
  STAGE_LOAD(0);
  STAGE_WRITE(0);
  STAGE_LOAD(1);
  bf16x8 bhA[4], blA[4], bhB[4], blB[4], ah[4];
  LOADB(0, bhA, blA);
  __syncthreads();

  for (int t = 0; t < NT; ++t) {
    const int cur = t & 1;
    if (t + 1 < NT) {
      STAGE_WRITE(cur ^ 1);          // tile t+1 -> other buffer
      LOADB(t + 1, bhB, blB);        // prefetch B(t+1)
    }
    if (t + 2 < NT) STAGE_LOAD(t + 2);
    READ_FRAGS(cur, ah);
    MFMAS(ah, bhA, blA);
#pragma unroll
    for (int s = 0; s < 4; ++s) { bhA[s] = bhB[s]; blA[s] = blB[s]; }
    __syncthreads();
  }

  // write relu(h1) as bf16 into LDS (C layout: row=(lane>>4)*4+q, col=lane&15)
#pragma unroll
  for (int mi = 0; mi < 4; ++mi)
#pragma unroll
    for (int s = 0; s < 4; ++s)
#pragma unroll
      for (int q = 0; q < 4; ++q) {
        int rr = mi * 16 + (g << 2) + q;
        int cc = (w << 6) + s * 16 + fr;
        h1s[rr * 264 + cc] = f2bf(fmaxf(acc[mi][s][q], 0.f));
      }
  __syncthreads();

  // phase B: h2 = h1 @ W2^T + b2, L2-normalize, store bf16 (padded to 64)
  const int br = tid & 63;
  const int cg = w;
  const int nj = (cg == 0) ? 11 : 10;
  float outs[11];
#pragma unroll
  for (int j = 0; j < 11; ++j) {
    int c = cg + 4 * j;
    outs[j] = (c < OUTC) ? b2[c] : 0.f;
  }

  for (int kc = 0; kc < 4; ++kc) {
    for (int e = tid; e < OUTC * 64; e += 256) {
      int c = e >> 6, kk = e & 63;
      W2s[c * 68 + kk] = W2[c * HID_C + kc * 64 + kk];
    }
    __syncthreads();
#pragma unroll 4
    for (int kk = 0; kk < 64; kk += 4) {
      const ushort4 hv = *(const ushort4*)&h1s[br * 264 + kc * 64 + kk];
      float h0v = bf2f(hv.x), h1v = bf2f(hv.y), h2v = bf2f(hv.z), h3v = bf2f(hv.w);
      for (int j = 0; j < nj; ++j) {
        const float4 wv = *(const float4*)&W2s[(cg + 4 * j) * 68 + kk];
        outs[j] += h0v * wv.x + h1v * wv.y + h2v * wv.z + h3v * wv.w;
      }
    }
    __syncthreads();
  }

  float ss = 0.f;
  for (int j = 0; j < nj; ++j) ss += outs[j] * outs[j];
  psum[br * 4 + cg] = ss;
  __syncthreads();
  if (tid < 64) {
    float s = psum[tid * 4] + psum[tid * 4 + 1] + psum[tid * 4 + 2] + psum[tid * 4 + 3];
    rnorm[tid] = 1.f / fmaxf(sqrtf(s), 1e-12f);
  }
  __syncthreads();
  const int gr = r0 + br;
  if (gr < N_NODES) {
    float rn = rnorm[br];
#pragma unroll
    for (int j = 0; j < 16; ++j) {
      int c = cg + 4 * j;
      float val = (j < nj) ? outs[j] * rn : 0.f;
      H0[(size_t)gr * HSTR + c] = f2bf(val);
    }
  }
}

// ---------------- exclusive scan (3 kernels) ----------------
__global__ __launch_bounds__(256) void scan1_kernel(const unsigned* __restrict__ deg,
                                                    unsigned* __restrict__ offs,
                                                    unsigned* __restrict__ btot) {
  __shared__ unsigned wsum[4];
  __shared__ unsigned wbase[4];
  const int t = threadIdx.x, lane = t & 63, w = t >> 6;
  const int base = blockIdx.x * 1024 + t * 4;
  unsigned v[4];
#pragma unroll
  for (int i = 0; i < 4; ++i) {
    int idx = base + i;
    v[i] = (idx < N_NODES) ? deg[idx] : 0u;
  }
  unsigned tsum = v[0] + v[1] + v[2] + v[3];
  unsigned inc = tsum;
  for (int d = 1; d < 64; d <<= 1) {
    unsigned n = (unsigned)__shfl_up((int)inc, d);
    if (lane >= d) inc += n;
  }
  if (lane == 63) wsum[w] = inc;
  __syncthreads();
  if (t == 0) {
    unsigned run = 0;
    for (int i = 0; i < 4; ++i) { unsigned s = wsum[i]; wbase[i] = run; run += s; }
    btot[blockIdx.x] = run;
  }
  __syncthreads();
  unsigned ex = wbase[w] + inc - tsum;
#pragma unroll
  for (int i = 0; i < 4; ++i) {
    int idx = base + i;
    if (idx < N_NODES) offs[idx] = ex;
    ex += v[i];
  }
}

__global__ __launch_bounds__(128) void scan2_kernel(const unsigned* __restrict__ btot,
                                                    unsigned* __restrict__ bbase, int B) {
  __shared__ unsigned wsum[2];
  __shared__ unsigned wbase[2];
  const int t = threadIdx.x, lane = t & 63, w = t >> 6;
  unsigned v = (t < B) ? btot[t] : 0u;
  unsigned inc = v;
  for (int d = 1; d < 64; d <<= 1) {
    unsigned n = (unsigned)__shfl_up((int)inc, d);
    if (lane >= d) inc += n;
  }
  if (lane == 63) wsum[w] = inc;
  __syncthreads();
  if (t == 0) {
    unsigned run = 0;
    for (int i = 0; i < 2; ++i) { unsigned s = wsum[i]; wbase[i] = run; run += s; }
  }
  __syncthreads();
  unsigned ex = wbase[w] + inc - v;
  if (t < B) bbase[t] = ex;
}

__global__ __launch_bounds__(256) void scan3_kernel(unsigned* __restrict__ offs,
                                                    const unsigned* __restrict__ bbase) {
  int i = blockIdx.x * 256 + threadIdx.x;
  if (i < N_NODES) offs[i] += bbase[i >> 10];
}

// ---------------- CSC scatter ----------------
__global__ __launch_bounds__(256) void scatter_kernel(const int* __restrict__ row,
                                                      const int* __restrict__ col,
                                                      const float* __restrict__ dinv,
                                                      const unsigned* __restrict__ offs,
                                                      unsigned* __restrict__ cursor,
                                                      int2* __restrict__ rec) {
  int e = blockIdx.x * 256 + threadIdx.x;
  if (e >= N_EDGES) return;
  int r = row[e], c = col[e];
  float wgt = dinv[r] * dinv[c];
  unsigned pos = offs[c] + atomicAdd(&cursor[c], 1u);
  rec[pos] = make_int2(r, __float_as_int(wgt));
}

// -------- APPNP iteration: 2 nodes/wave, packed-uint bf16 gathers --------
__global__ __launch_bounds__(256) void prop_kernel(
    const unsigned short* __restrict__ hsrc,
    const unsigned short* __restrict__ h0,
    unsigned short* __restrict__ hdst,   // used when fout == nullptr
    float* __restrict__ fout,            // non-null on last iteration
    const int2* __restrict__ rec,
    const unsigned* __restrict__ offs,
    const unsigned* __restrict__ deg,
    const float* __restrict__ dinv) {
  const int wv = threadIdx.x >> 6;
  const int lane = threadIdx.x & 63;
  const int half = lane >> 5;
  const int h = lane & 31;             // uint index within 128-B row
  const int n = blockIdx.x * 8 + wv * 2 + half;
  if (n >= N_NODES) return;
  const unsigned* hs = (const unsigned*)hsrc;
  const unsigned s = offs[n];
  const unsigned e = s + deg[n];
  float a0 = 0.f, a1 = 0.f, b0 = 0.f, b1 = 0.f;
  unsigned i = s;
  for (; i + 8 <= e; i += 8) {
    int2 q0 = rec[i],     q1 = rec[i + 1], q2 = rec[i + 2], q3 = rec[i + 3];
    int2 q4 = rec[i + 4], q5 = rec[i + 5], q6 = rec[i + 6], q7 = rec[i + 7];
    unsigned u0 = hs[(size_t)q0.x * 32 + h];
    unsigned u1 = hs[(size_t)q1.x * 32 + h];
    unsigned u2 = hs[(size_t)q2.x * 32 + h];
    unsigned u3 = hs[(size_t)q3.x * 32 + h];
    unsigned u4 = hs[(size_t)q4.x * 32 + h];
    unsigned u5 = hs[(size_t)q5.x * 32 + h];
    unsigned u6 = hs[(size_t)q6.x * 32 + h];
    unsigned u7 = hs[(size_t)q7.x * 32 + h];
    float w0 = __int_as_float(q0.y), w1 = __int_as_float(q1.y);
    float w2 = __int_as_float(q2.y), w3 = __int_as_float(q3.y);
    float w4 = __int_as_float(q4.y), w5 = __int_as_float(q5.y);
    float w6 = __int_as_float(q6.y), w7 = __int_as_float(q7.y);
    a0 += bflo(u0) * w0; a1 += bfhi(u0) * w0;
    b0 += bflo(u1) * w1; b1 += bfhi(u1) * w1;
    a0 += bflo(u2) * w2; a1 += bfhi(u2) * w2;
    b0 += bflo(u3) * w3; b1 += bfhi(u3) * w3;
    a0 += bflo(u4) * w4; a1 += bfhi(u4) * w4;
    b0 += bflo(u5) * w5; b1 += bfhi(u5) * w5;
    a0 += bflo(u6) * w6; a1 += bfhi(u6) * w6;
    b0 += bflo(u7) * w7; b1 += bfhi(u7) * w7;
  }
  for (; i < e; ++i) {
    int2 q = rec[i];
    unsigned u = hs[(size_t)q.x * 32 + h];
    float wq = __int_as_float(q.y);
    a0 += bflo(u) * wq; a1 += bfhi(u) * wq;
  }
  float di = dinv[n];
  unsigned su = hs[(size_t)n * 32 + h];
  a0 += bflo(su) * di * di;
  a1 += bfhi(su) * di * di;
  unsigned hu = ((const unsigned*)h0)[(size_t)n * 32 + h];
  float o0 = 0.9f * (a0 + b0) + 0.1f * bflo(hu);
  float o1 = 0.9f * (a1 + b1) + 0.1f * bfhi(hu);
  if (fout) {
    int c = 2 * h;
    if (c < OUTC) fout[(size_t)n * OUTC + c] = o0;
    if (c + 1 < OUTC) fout[(size_t)n * OUTC + c + 1] = o1;
  } else {
    unsigned pk = (unsigned)f2bf(o0) | ((unsigned)f2bf(o1) << 16);
    ((unsigned*)hdst)[(size_t)n * 32 + h] = pk;
  }
}

// ---------------- host ----------------
extern "C" void kernel_launch(void* const* d_in, const int* in_sizes, int n_in,
                              void* d_out, int out_size, void* d_ws, size_t ws_size,
                              hipStream_t stream) {
  const float* x  = (const float*)d_in[0];
  const int*   ei = (const int*)d_in[1];
  const float* W1 = (const float*)d_in[2];
  const float* b1 = (const float*)d_in[3];
  const float* W2 = (const float*)d_in[4];
  const float* b2 = (const float*)d_in[5];
  float* out = (float*)d_out;

  char* p = (char*)d_ws;
  auto alloc = [&](size_t bytes) {
    char* q = p;
    p += (bytes + 255) & ~(size_t)255;
    return q;
  };
  unsigned* deg    = (unsigned*)alloc((size_t)N_NODES * 4);
  float*    dinv   = (float*)   alloc((size_t)N_NODES * 4);
  unsigned* offs   = (unsigned*)alloc((size_t)N_NODES * 4);
  unsigned* btot   = (unsigned*)alloc(128 * 4);
  unsigned* bbase  = (unsigned*)alloc(128 * 4);
  unsigned* cursor = (unsigned*)alloc((size_t)N_NODES * 4);
  int2*     rec    = (int2*)    alloc((size_t)N_EDGES * 8);
  unsigned short* H0 = (unsigned short*)alloc((size_t)N_NODES * HSTR * 2);
  unsigned short* HA = (unsigned short*)alloc((size_t)N_NODES * HSTR * 2);
  unsigned short* HB = (unsigned short*)alloc((size_t)N_NODES * HSTR * 2);
  unsigned short* Whf = (unsigned short*)alloc((size_t)HID_C * KPAD * 2);
  unsigned short* Wlf = (unsigned short*)alloc((size_t)HID_C * KPAD * 2);

  const int* row = ei;            // edge_index[0] : sources
  const int* col = ei + N_EDGES;  // edge_index[1] : targets

  hipMemsetAsync(deg, 0, (size_t)N_NODES * 4, stream);
  hipMemsetAsync(cursor, 0, (size_t)N_NODES * 4, stream);

  deg_kernel<<<(N_EDGES + 255) / 256, 256, 0, stream>>>(col, deg);
  dinv_kernel<<<(N_NODES + 255) / 256, 256, 0, stream>>>(deg, dinv);
  wprep_kernel<<<(HID_C * KPAD + 255) / 256, 256, 0, stream>>>(W1, Whf, Wlf);
  mlp_kernel<<<(N_NODES + 63) / 64, 256, 0, stream>>>(x, Whf, Wlf, b1, W2, b2, H0);

  const int B = (N_NODES + 1023) / 1024;  // 98
  scan1_kernel<<<B, 256, 0, stream>>>(deg, offs, btot);
  scan2_kernel<<<1, 128, 0, stream>>>(btot, bbase, B);
  scan3_kernel<<<(N_NODES + 255) / 256, 256, 0, stream>>>(offs, bbase);
  scatter_kernel<<<(N_EDGES + 255) / 256, 256, 0, stream>>>(row, col, dinv, offs, cursor, rec);

  const unsigned short* src = H0;
  unsigned short* bufs[2] = {HA, HB};
  for (int k = 0; k < K_ITERS; ++k) {
    bool last = (k == K_ITERS - 1);
    unsigned short* dst = last ? nullptr : bufs[k & 1];
    float* fdst = last ? out : nullptr;
    prop_kernel<<<(N_NODES + 7) / 8, 256, 0, stream>>>(src, H0, dst, fdst, rec, offs, deg, dinv);
    src = dst;
  }
}

// Round 7
// 1201.543 us; speedup vs baseline: 3.2098x; 1.1675x over previous
//
#include <hip/hip_runtime.h>

#define N_NODES 100000
#define N_EDGES 3200000
#define IN_C 602
#define KPAD 608
#define NT 19           // KPAD/32 k-tiles
#define HID_C 256
#define OUTC 41
#define HSTR 64         // bf16 h row stride (128 B = 2 cache lines)
#define K_ITERS 10

typedef __attribute__((ext_vector_type(8))) short bf16x8;
typedef __attribute__((ext_vector_type(4))) float f32x4;

static __device__ __forceinline__ unsigned short f2bf(float f) {
  unsigned u = __float_as_uint(f);
  u += 0x7fffu + ((u >> 16) & 1u);
  return (unsigned short)(u >> 16);
}
static __device__ __forceinline__ float bf2f(unsigned short h) {
  return __uint_as_float(((unsigned)h) << 16);
}
static __device__ __forceinline__ float bflo(unsigned u) {
  return __uint_as_float(u << 16);
}
static __device__ __forceinline__ float bfhi(unsigned u) {
  return __uint_as_float(u & 0xffff0000u);
}

// ---------------- degree ----------------
__global__ __launch_bounds__(256) void deg_kernel(const int* __restrict__ col,
                                                  unsigned* __restrict__ deg) {
  int e = blockIdx.x * 256 + threadIdx.x;
  if (e < N_EDGES) atomicAdd(&deg[col[e]], 1u);
}

__global__ __launch_bounds__(256) void dinv_kernel(const unsigned* __restrict__ deg,
                                                   float* __restrict__ dinv) {
  int i = blockIdx.x * 256 + threadIdx.x;
  if (i < N_NODES) dinv[i] = rsqrtf((float)(deg[i] + 1u));
}

// ------- W1 bf16 (nearest) in fragment-linear layout [t][n][g][8] --------
__global__ __launch_bounds__(256) void wprep1_kernel(const float* __restrict__ W1,
                                                     unsigned short* __restrict__ Whf) {
  int idx = blockIdx.x * 256 + threadIdx.x;
  if (idx >= HID_C * KPAD) return;
  int n = idx / KPAD, k = idx % KPAD;
  float v = (k < IN_C) ? W1[n * IN_C + k] : 0.f;
  int t = k >> 5, g = (k >> 3) & 3, j = k & 7;
  Whf[(size_t)t * 8192 + (((n << 2) + g) << 3) + j] = f2bf(v);
}

// ------- W2 hi/lo split, fragment-linear [ks][n(48)][g][8] ---------------
__global__ __launch_bounds__(256) void wprep2_kernel(const float* __restrict__ W2,
                                                     unsigned short* __restrict__ W2hf,
                                                     unsigned short* __restrict__ W2lf) {
  int idx = blockIdx.x * 256 + threadIdx.x;
  if (idx >= 48 * HID_C) return;
  int n = idx >> 8, k = idx & 255;
  float v = (n < OUTC) ? W2[n * HID_C + k] : 0.f;
  unsigned short hi = f2bf(v);
  int ks = k >> 5, g = (k >> 3) & 3, j = k & 7;
  size_t dst = (size_t)ks * 1536 + (((n << 2) + g) << 3) + j;
  W2hf[dst] = hi;
  W2lf[dst] = f2bf(v - bf2f(hi));
}

// ---------------- GEMM1: h1 = relu(x @ W1^T + b1), bf16 out --------------
// Triple-buffered LDS staging, parity B-regs, x split hi/lo in-register.
__global__ __launch_bounds__(256, 3) void gemm1_kernel(
    const float* __restrict__ x,
    const unsigned short* __restrict__ Whf,
    const float* __restrict__ b1,
    unsigned short* __restrict__ h1g) {
  __shared__ __align__(16) float4 xt[3 * 512];        // 24 KB; reused as h1t
  unsigned short* h1t = (unsigned short*)xt;          // [32][264] in epilogue

  const int tid = threadIdx.x;
  const int lane = tid & 63;
  const int w = tid >> 6;
  const int r0 = blockIdx.x * 64;
  const int fr = lane & 15;
  const int g = lane >> 4;

  // staging geometry
  const int srow = tid >> 3;
  const int sc = tid & 7;
  int gr0 = r0 + srow;       if (gr0 >= N_NODES) gr0 = N_NODES - 1;
  int gr1 = r0 + srow + 32;  if (gr1 >= N_NODES) gr1 = N_NODES - 1;
  const float* xp0 = x + (size_t)gr0 * IN_C;
  const float* xp1 = x + (size_t)gr1 * IN_C;
  const int ws0 = srow * 8 + (sc ^ (srow & 7));
  const int ws1 = (srow + 32) * 8 + (sc ^ (srow & 7));

  f32x4 acc[4][4];
  {
    const int bcol0 = (w << 6) + fr;
#pragma unroll
    for (int s = 0; s < 4; ++s) {
      float bv = b1[bcol0 + s * 16];
#pragma unroll
      for (int mi = 0; mi < 4; ++mi) acc[mi][s] = (f32x4){bv, bv, bv, bv};
    }
  }

  float4 pA0, pA1, pB0, pB1;  // staging pairs: pair0=(pA0,pA1), pair1=(pB0,pB1)
  bf16x8 bhv[2][4];

#define STAGE_LOAD0(T)                                                     \
  { const int kb = (T) * 32 + sc * 4;                                      \
    if ((T) < NT - 1) { pA0 = *(const float4*)(xp0 + kb);                  \
                        pA1 = *(const float4*)(xp1 + kb); }                \
    else { float t0[4], t1[4];                                             \
      _Pragma("unroll") for (int j = 0; j < 4; ++j) { int k = kb + j;      \
        t0[j] = (k < IN_C) ? xp0[k] : 0.f; t1[j] = (k < IN_C) ? xp1[k] : 0.f; } \
      pA0 = (float4){t0[0], t0[1], t0[2], t0[3]};                          \
      pA1 = (float4){t1[0], t1[1], t1[2], t1[3]}; } }

#define STAGE_LOAD1(T)                                                     \
  { const int kb = (T) * 32 + sc * 4;                                      \
    if ((T) < NT - 1) { pB0 = *(const float4*)(xp0 + kb);                  \
                        pB1 = *(const float4*)(xp1 + kb); }                \
    else { float t0[4], t1[4];                                             \
      _Pragma("unroll") for (int j = 0; j < 4; ++j) { int k = kb + j;      \
        t0[j] = (k < IN_C) ? xp0[k] : 0.f; t1[j] = (k < IN_C) ? xp1[k] : 0.f; } \
      pB0 = (float4){t0[0], t0[1], t0[2], t0[3]};                          \
      pB1 = (float4){t1[0], t1[1], t1[2], t1[3]}; } }

#define STAGE_WRITE0(BW) { xt[(BW) * 512 + ws0] = pA0; xt[(BW) * 512 + ws1] = pA1; }
#define STAGE_WRITE1(BW) { xt[(BW) * 512 + ws0] = pB0; xt[(BW) * 512 + ws1] = pB1; }

#define LOADB(T, PAR)                                                      \
  { const size_t tb = (size_t)(T) * 8192;                                  \
    _Pragma("unroll") for (int s = 0; s < 4; ++s) {                        \
      const int n4 = (((w << 6) + s * 16 + fr) << 2) + g;                  \
      bhv[PAR][s] = *(const bf16x8*)(Whf + tb + n4 * 8);                   \
    } }

#define COMPUTE(BR, PAR)                                                   \
  { _Pragma("unroll") for (int mi = 0; mi < 4; ++mi) {                     \
      const int rr = mi * 16 + fr;                                         \
      float4 pa = xt[(BR) * 512 + rr * 8 + ((2 * g) ^ (fr & 7))];          \
      float4 pb = xt[(BR) * 512 + rr * 8 + ((2 * g + 1) ^ (fr & 7))];      \
      union { unsigned u[4]; bf16x8 v; } hh, ll;                           \
      asm("v_cvt_pk_bf16_f32 %0, %1, %2" : "=v"(hh.u[0]) : "v"(pa.x), "v"(pa.y)); \
      asm("v_cvt_pk_bf16_f32 %0, %1, %2" : "=v"(hh.u[1]) : "v"(pa.z), "v"(pa.w)); \
      asm("v_cvt_pk_bf16_f32 %0, %1, %2" : "=v"(hh.u[2]) : "v"(pb.x), "v"(pb.y)); \
      asm("v_cvt_pk_bf16_f32 %0, %1, %2" : "=v"(hh.u[3]) : "v"(pb.z), "v"(pb.w)); \
      float l0 = pa.x - bflo(hh.u[0]), l1 = pa.y - bfhi(hh.u[0]);          \
      float l2 = pa.z - bflo(hh.u[1]), l3 = pa.w - bfhi(hh.u[1]);          \
      float l4 = pb.x - bflo(hh.u[2]), l5 = pb.y - bfhi(hh.u[2]);          \
      float l6 = pb.z - bflo(hh.u[3]), l7 = pb.w - bfhi(hh.u[3]);          \
      asm("v_cvt_pk_bf16_f32 %0, %1, %2" : "=v"(ll.u[0]) : "v"(l0), "v"(l1)); \
      asm("v_cvt_pk_bf16_f32 %0, %1, %2" : "=v"(ll.u[1]) : "v"(l2), "v"(l3)); \
      asm("v_cvt_pk_bf16_f32 %0, %1, %2" : "=v"(ll.u[2]) : "v"(l4), "v"(l5)); \
      asm("v_cvt_pk_bf16_f32 %0, %1, %2" : "=v"(ll.u[3]) : "v"(l6), "v"(l7)); \
      _Pragma("unroll") for (int s = 0; s < 4; ++s) {                      \
        acc[mi][s] = __builtin_amdgcn_mfma_f32_16x16x32_bf16(              \
            hh.v, bhv[PAR][s], acc[mi][s], 0, 0, 0);                       \
        acc[mi][s] = __builtin_amdgcn_mfma_f32_16x16x32_bf16(              \
            ll.v, bhv[PAR][s], acc[mi][s], 0, 0, 0);                       \
      } } }

#define BODY(T, PAR)                                                       \
  { int bW = bR + 1; if (bW == 3) bW = 0;                                  \
    if ((T) + 1 < NT) {                                                    \
      if ((PAR) == 0) STAGE_WRITE1(bW) else STAGE_WRITE0(bW);              \
      if ((T) + 3 < NT) { if ((PAR) == 0) STAGE_LOAD1((T) + 3)             \
                          else STAGE_LOAD0((T) + 3); }                     \
      LOADB((T) + 1, (PAR) ^ 1);                                           \
    }                                                                      \
    COMPUTE(bR, PAR);                                                      \
    __syncthreads();                                                       \
    bR = bW; }

  // prologue: tiles 0,1,2 loaded; buf0 written; B(0) in regs
  STAGE_LOAD0(0);
  STAGE_WRITE0(0);
  STAGE_LOAD1(1);
  STAGE_LOAD0(2);
  LOADB(0, 0);
  __syncthreads();

  int bR = 0;
  for (int t = 0; t + 1 < NT; t += 2) {
    BODY(t, 0);
    BODY(t + 1, 1);
  }
  BODY(NT - 1, 0);  // NT odd: tail tile, parity 0

  // epilogue: coalesced h1 store via 2 LDS chunks of 32 rows
#pragma unroll
  for (int ch = 0; ch < 2; ++ch) {
#pragma unroll
    for (int mi2 = 0; mi2 < 2; ++mi2) {
      const int mi = ch * 2 + mi2;
#pragma unroll
      for (int s = 0; s < 4; ++s)
#pragma unroll
        for (int q = 0; q < 4; ++q) {
          int rr = mi2 * 16 + (g << 2) + q;
          int cc = (w << 6) + s * 16 + fr;
          h1t[rr * 264 + cc] = f2bf(fmaxf(acc[mi][s][q], 0.f));
        }
    }
    __syncthreads();
    {
      const int row = tid >> 3, seg = tid & 7;
      const int gr = r0 + ch * 32 + row;
      if (gr < N_NODES) {
        const uint4* src = (const uint4*)&h1t[row * 264 + seg * 32];
        uint4* dst = (uint4*)(h1g + (size_t)gr * 256 + seg * 32);
        dst[0] = src[0];   // 32 shorts = 64 B = 4 x uint4 (R6 bug: only 2 stored)
        dst[1] = src[1];
        dst[2] = src[2];
        dst[3] = src[3];
      }
    }
    __syncthreads();
  }
}

// ------- GEMM2 + L2 norm: H0 = normalize(h1 @ W2^T + b2), bf16 out -------
__global__ __launch_bounds__(256) void gemm2_kernel(
    const unsigned short* __restrict__ h1g,
    const unsigned short* __restrict__ W2hf,
    const unsigned short* __restrict__ W2lf,
    const float* __restrict__ b2,
    unsigned short* __restrict__ H0) {
  const int tid = threadIdx.x;
  const int lane = tid & 63;
  const int w = tid >> 6;
  const int fr = lane & 15;
  const int g = lane >> 4;
  const int wr0 = blockIdx.x * 64 + w * 16;

  f32x4 acc[3];
#pragma unroll
  for (int s = 0; s < 3; ++s) {
    int c = s * 16 + fr;
    float bv = (c < OUTC) ? b2[c] : 0.f;
    acc[s] = (f32x4){bv, bv, bv, bv};
  }

  int ar = wr0 + fr;
  if (ar >= N_NODES) ar = N_NODES - 1;
  const unsigned short* ap = h1g + (size_t)ar * 256 + g * 8;

#pragma unroll
  for (int ks = 0; ks < 8; ++ks) {
    bf16x8 a = *(const bf16x8*)(ap + ks * 32);
#pragma unroll
    for (int s = 0; s < 3; ++s) {
      const int n4 = (((s * 16 + fr) << 2) + g) << 3;
      bf16x8 bh = *(const bf16x8*)(W2hf + (size_t)ks * 1536 + n4);
      bf16x8 bl = *(const bf16x8*)(W2lf + (size_t)ks * 1536 + n4);
      acc[s] = __builtin_amdgcn_mfma_f32_16x16x32_bf16(a, bh, acc[s], 0, 0, 0);
      acc[s] = __builtin_amdgcn_mfma_f32_16x16x32_bf16(a, bl, acc[s], 0, 0, 0);
    }
  }

  // per-row (g*4+q) sum of squares, reduced over the 16 fr-lanes
  float ps[4];
#pragma unroll
  for (int q = 0; q < 4; ++q)
    ps[q] = acc[0][q] * acc[0][q] + acc[1][q] * acc[1][q] + acc[2][q] * acc[2][q];
#pragma unroll
  for (int m = 1; m < 16; m <<= 1)
#pragma unroll
    for (int q = 0; q < 4; ++q) ps[q] += __shfl_xor(ps[q], m);

#pragma unroll
  for (int q = 0; q < 4; ++q) {
    const int gr = wr0 + (g << 2) + q;
    if (gr < N_NODES) {
      float rn = 1.f / fmaxf(sqrtf(ps[q]), 1e-12f);
#pragma unroll
      for (int s = 0; s < 3; ++s)
        H0[(size_t)gr * HSTR + s * 16 + fr] = f2bf(acc[s][q] * rn);
      H0[(size_t)gr * HSTR + 48 + fr] = 0;
    }
  }
}

// ---------------- exclusive scan (3 kernels) ----------------
__global__ __launch_bounds__(256) void scan1_kernel(const unsigned* __restrict__ deg,
                                                    unsigned* __restrict__ offs,
                                                    unsigned* __restrict__ btot) {
  __shared__ unsigned wsum[4];
  __shared__ unsigned wbase[4];
  const int t = threadIdx.x, lane = t & 63, w = t >> 6;
  const int base = blockIdx.x * 1024 + t * 4;
  unsigned v[4];
#pragma unroll
  for (int i = 0; i < 4; ++i) {
    int idx = base + i;
    v[i] = (idx < N_NODES) ? deg[idx] : 0u;
  }
  unsigned tsum = v[0] + v[1] + v[2] + v[3];
  unsigned inc = tsum;
  for (int d = 1; d < 64; d <<= 1) {
    unsigned n = (unsigned)__shfl_up((int)inc, d);
    if (lane >= d) inc += n;
  }
  if (lane == 63) wsum[w] = inc;
  __syncthreads();
  if (t == 0) {
    unsigned run = 0;
    for (int i = 0; i < 4; ++i) { unsigned s = wsum[i]; wbase[i] = run; run += s; }
    btot[blockIdx.x] = run;
  }
  __syncthreads();
  unsigned ex = wbase[w] + inc - tsum;
#pragma unroll
  for (int i = 0; i < 4; ++i) {
    int idx = base + i;
    if (idx < N_NODES) offs[idx] = ex;
    ex += v[i];
  }
}

__global__ __launch_bounds__(128) void scan2_kernel(const unsigned* __restrict__ btot,
                                                    unsigned* __restrict__ bbase, int B) {
  __shared__ unsigned wsum[2];
  __shared__ unsigned wbase[2];
  const int t = threadIdx.x, lane = t & 63, w = t >> 6;
  unsigned v = (t < B) ? btot[t] : 0u;
  unsigned inc = v;
  for (int d = 1; d < 64; d <<= 1) {
    unsigned n = (unsigned)__shfl_up((int)inc, d);
    if (lane >= d) inc += n;
  }
  if (lane == 63) wsum[w] = inc;
  __syncthreads();
  if (t == 0) {
    unsigned run = 0;
    for (int i = 0; i < 2; ++i) { unsigned s = wsum[i]; wbase[i] = run; run += s; }
  }
  __syncthreads();
  unsigned ex = wbase[w] + inc - v;
  if (t < B) bbase[t] = ex;
}

__global__ __launch_bounds__(256) void scan3_kernel(unsigned* __restrict__ offs,
                                                    const unsigned* __restrict__ bbase) {
  int i = blockIdx.x * 256 + threadIdx.x;
  if (i < N_NODES) offs[i] += bbase[i >> 10];
}

// ---------------- CSC scatter ----------------
__global__ __launch_bounds__(256) void scatter_kernel(const int* __restrict__ row,
                                                      const int* __restrict__ col,
                                                      const float* __restrict__ dinv,
                                                      const unsigned* __restrict__ offs,
                                                      unsigned* __restrict__ cursor,
                                                      int2* __restrict__ rec) {
  int e = blockIdx.x * 256 + threadIdx.x;
  if (e >= N_EDGES) return;
  int r = row[e], c = col[e];
  float wgt = dinv[r] * dinv[c];
  unsigned pos = offs[c] + atomicAdd(&cursor[c], 1u);
  rec[pos] = make_int2(r, __float_as_int(wgt));
}

// -------- APPNP iteration: 2 nodes/wave, packed-uint bf16 gathers --------
__global__ __launch_bounds__(256) void prop_kernel(
    const unsigned short* __restrict__ hsrc,
    const unsigned short* __restrict__ h0,
    unsigned short* __restrict__ hdst,   // used when fout == nullptr
    float* __restrict__ fout,            // non-null on last iteration
    const int2* __restrict__ rec,
    const unsigned* __restrict__ offs,
    const unsigned* __restrict__ deg,
    const float* __restrict__ dinv) {
  const int wv = threadIdx.x >> 6;
  const int lane = threadIdx.x & 63;
  const int half = lane >> 5;
  const int h = lane & 31;             // uint index within 128-B row
  const int n = blockIdx.x * 8 + wv * 2 + half;
  if (n >= N_NODES) return;
  const unsigned* hs = (const unsigned*)hsrc;
  const unsigned s = offs[n];
  const unsigned e = s + deg[n];
  float a0 = 0.f, a1 = 0.f, b0 = 0.f, b1 = 0.f;
  unsigned i = s;
  for (; i + 8 <= e; i += 8) {
    int2 q0 = rec[i],     q1 = rec[i + 1], q2 = rec[i + 2], q3 = rec[i + 3];
    int2 q4 = rec[i + 4], q5 = rec[i + 5], q6 = rec[i + 6], q7 = rec[i + 7];
    unsigned u0 = hs[(size_t)q0.x * 32 + h];
    unsigned u1 = hs[(size_t)q1.x * 32 + h];
    unsigned u2 = hs[(size_t)q2.x * 32 + h];
    unsigned u3 = hs[(size_t)q3.x * 32 + h];
    unsigned u4 = hs[(size_t)q4.x * 32 + h];
    unsigned u5 = hs[(size_t)q5.x * 32 + h];
    unsigned u6 = hs[(size_t)q6.x * 32 + h];
    unsigned u7 = hs[(size_t)q7.x * 32 + h];
    float w0 = __int_as_float(q0.y), w1 = __int_as_float(q1.y);
    float w2 = __int_as_float(q2.y), w3 = __int_as_float(q3.y);
    float w4 = __int_as_float(q4.y), w5 = __int_as_float(q5.y);
    float w6 = __int_as_float(q6.y), w7 = __int_as_float(q7.y);
    a0 += bflo(u0) * w0; a1 += bfhi(u0) * w0;
    b0 += bflo(u1) * w1; b1 += bfhi(u1) * w1;
    a0 += bflo(u2) * w2; a1 += bfhi(u2) * w2;
    b0 += bflo(u3) * w3; b1 += bfhi(u3) * w3;
    a0 += bflo(u4) * w4; a1 += bfhi(u4) * w4;
    b0 += bflo(u5) * w5; b1 += bfhi(u5) * w5;
    a0 += bflo(u6) * w6; a1 += bfhi(u6) * w6;
    b0 += bflo(u7) * w7; b1 += bfhi(u7) * w7;
  }
  for (; i < e; ++i) {
    int2 q = rec[i];
    unsigned u = hs[(size_t)q.x * 32 + h];
    float wq = __int_as_float(q.y);
    a0 += bflo(u) * wq; a1 += bfhi(u) * wq;
  }
  float di = dinv[n];
  unsigned su = hs[(size_t)n * 32 + h];
  a0 += bflo(su) * di * di;
  a1 += bfhi(su) * di * di;
  unsigned hu = ((const unsigned*)h0)[(size_t)n * 32 + h];
  float o0 = 0.9f * (a0 + b0) + 0.1f * bflo(hu);
  float o1 = 0.9f * (a1 + b1) + 0.1f * bfhi(hu);
  if (fout) {
    int c = 2 * h;
    if (c < OUTC) fout[(size_t)n * OUTC + c] = o0;
    if (c + 1 < OUTC) fout[(size_t)n * OUTC + c + 1] = o1;
  } else {
    unsigned pk = (unsigned)f2bf(o0) | ((unsigned)f2bf(o1) << 16);
    ((unsigned*)hdst)[(size_t)n * 32 + h] = pk;
  }
}

// ---------------- host ----------------
extern "C" void kernel_launch(void* const* d_in, const int* in_sizes, int n_in,
                              void* d_out, int out_size, void* d_ws, size_t ws_size,
                              hipStream_t stream) {
  const float* x  = (const float*)d_in[0];
  const int*   ei = (const int*)d_in[1];
  const float* W1 = (const float*)d_in[2];
  const float* b1 = (const float*)d_in[3];
  const float* W2 = (const float*)d_in[4];
  const float* b2 = (const float*)d_in[5];
  float* out = (float*)d_out;

  char* p = (char*)d_ws;
  auto alloc = [&](size_t bytes) {
    char* q = p;
    p += (bytes + 255) & ~(size_t)255;
    return q;
  };
  unsigned* deg    = (unsigned*)alloc((size_t)N_NODES * 4);
  float*    dinv   = (float*)   alloc((size_t)N_NODES * 4);
  unsigned* offs   = (unsigned*)alloc((size_t)N_NODES * 4);
  unsigned* btot   = (unsigned*)alloc(128 * 4);
  unsigned* bbase  = (unsigned*)alloc(128 * 4);
  unsigned* cursor = (unsigned*)alloc((size_t)N_NODES * 4);
  int2*     rec    = (int2*)    alloc((size_t)N_EDGES * 8);
  unsigned short* H0  = (unsigned short*)alloc((size_t)N_NODES * HSTR * 2);
  unsigned short* HA  = (unsigned short*)alloc((size_t)N_NODES * HSTR * 2);
  unsigned short* HB  = (unsigned short*)alloc((size_t)N_NODES * HSTR * 2);
  unsigned short* h1g = (unsigned short*)alloc((size_t)N_NODES * HID_C * 2);
  unsigned short* Whf = (unsigned short*)alloc((size_t)NT * 8192 * 2);
  unsigned short* W2hf = (unsigned short*)alloc((size_t)8 * 1536 * 2);
  unsigned short* W2lf = (unsigned short*)alloc((size_t)8 * 1536 * 2);

  const int* row = ei;            // edge_index[0] : sources
  const int* col = ei + N_EDGES;  // edge_index[1] : targets

  hipMemsetAsync(deg, 0, (size_t)N_NODES * 4, stream);
  hipMemsetAsync(cursor, 0, (size_t)N_NODES * 4, stream);

  deg_kernel<<<(N_EDGES + 255) / 256, 256, 0, stream>>>(col, deg);
  dinv_kernel<<<(N_NODES + 255) / 256, 256, 0, stream>>>(deg, dinv);
  wprep1_kernel<<<(HID_C * KPAD + 255) / 256, 256, 0, stream>>>(W1, Whf);
  wprep2_kernel<<<(48 * HID_C + 255) / 256, 256, 0, stream>>>(W2, W2hf, W2lf);
  gemm1_kernel<<<(N_NODES + 63) / 64, 256, 0, stream>>>(x, Whf, b1, h1g);
  gemm2_kernel<<<(N_NODES + 63) / 64, 256, 0, stream>>>(h1g, W2hf, W2lf, b2, H0);

  const int B = (N_NODES + 1023) / 1024;  // 98
  scan1_kernel<<<B, 256, 0, stream>>>(deg, offs, btot);
  scan2_kernel<<<1, 128, 0, stream>>>(btot, bbase, B);
  scan3_kernel<<<(N_NODES + 255) / 256, 256, 0, stream>>>(offs, bbase);
  scatter_kernel<<<(N_EDGES + 255) / 256, 256, 0, stream>>>(row, col, dinv, offs, cursor, rec);

  const unsigned short* src = H0;
  unsigned short* bufs[2] = {HA, HB};
  for (int k = 0; k < K_ITERS; ++k) {
    bool last = (k == K_ITERS - 1);
    unsigned short* dst = last ? nullptr : bufs[k & 1];
    float* fdst = last ? out : nullptr;
    prop_kernel<<<(N_NODES + 7) / 8, 256, 0, stream>>>(src, H0, dst, fdst, rec, offs, deg, dinv);
    src = dst;
  }
}

// Round 8
// 935.371 us; speedup vs baseline: 4.1232x; 1.2846x over previous
//
#include <hip/hip_runtime.h>

#define N_NODES 100000
#define N_EDGES 3200000
#define IN_C 602
#define KPAD 608
#define NT 19           // KPAD/32 k-tiles
#define HID_C 256
#define OUTC 41
#define HSTR 64         // bf16 h0 row stride (128 B)
#define K_ITERS 10

typedef __attribute__((ext_vector_type(8))) short bf16x8;
typedef __attribute__((ext_vector_type(4))) float f32x4;
typedef __attribute__((ext_vector_type(2))) float f32x2;

static __device__ __forceinline__ unsigned short f2bf(float f) {
  unsigned u = __float_as_uint(f);
  u += 0x7fffu + ((u >> 16) & 1u);
  return (unsigned short)(u >> 16);
}
static __device__ __forceinline__ float bf2f(unsigned short h) {
  return __uint_as_float(((unsigned)h) << 16);
}
static __device__ __forceinline__ float bflo(unsigned u) {
  return __uint_as_float(u << 16);
}
static __device__ __forceinline__ float bfhi(unsigned u) {
  return __uint_as_float(u & 0xffff0000u);
}

// ---------------- degree ----------------
__global__ __launch_bounds__(256) void deg_kernel(const int* __restrict__ col,
                                                  unsigned* __restrict__ deg) {
  int e = blockIdx.x * 256 + threadIdx.x;
  if (e < N_EDGES) atomicAdd(&deg[col[e]], 1u);
}

__global__ __launch_bounds__(256) void dinv_kernel(const unsigned* __restrict__ deg,
                                                   float* __restrict__ dinv) {
  int i = blockIdx.x * 256 + threadIdx.x;
  if (i < N_NODES) dinv[i] = rsqrtf((float)(deg[i] + 1u));
}

// ------- W1 bf16 (nearest) in fragment-linear layout [t][n][g][8] --------
__global__ __launch_bounds__(256) void wprep1_kernel(const float* __restrict__ W1,
                                                     unsigned short* __restrict__ Whf) {
  int idx = blockIdx.x * 256 + threadIdx.x;
  if (idx >= HID_C * KPAD) return;
  int n = idx / KPAD, k = idx % KPAD;
  float v = (k < IN_C) ? W1[n * IN_C + k] : 0.f;
  int t = k >> 5, g = (k >> 3) & 3, j = k & 7;
  Whf[(size_t)t * 8192 + (((n << 2) + g) << 3) + j] = f2bf(v);
}

// ------- W2 hi/lo split, fragment-linear [ks][n(48)][g][8] ---------------
__global__ __launch_bounds__(256) void wprep2_kernel(const float* __restrict__ W2,
                                                     unsigned short* __restrict__ W2hf,
                                                     unsigned short* __restrict__ W2lf) {
  int idx = blockIdx.x * 256 + threadIdx.x;
  if (idx >= 48 * HID_C) return;
  int n = idx >> 8, k = idx & 255;
  float v = (n < OUTC) ? W2[n * HID_C + k] : 0.f;
  unsigned short hi = f2bf(v);
  int ks = k >> 5, g = (k >> 3) & 3, j = k & 7;
  size_t dst = (size_t)ks * 1536 + (((n << 2) + g) << 3) + j;
  W2hf[dst] = hi;
  W2lf[dst] = f2bf(v - bf2f(hi));
}

// ---------------- GEMM1: h1 = relu(x @ W1^T + b1), bf16 out --------------
__global__ __launch_bounds__(256, 3) void gemm1_kernel(
    const float* __restrict__ x,
    const unsigned short* __restrict__ Whf,
    const float* __restrict__ b1,
    unsigned short* __restrict__ h1g) {
  __shared__ __align__(16) float4 xt[3 * 512];        // 24 KB; reused as h1t
  unsigned short* h1t = (unsigned short*)xt;          // [32][264] in epilogue

  const int tid = threadIdx.x;
  const int lane = tid & 63;
  const int w = tid >> 6;
  const int r0 = blockIdx.x * 64;
  const int fr = lane & 15;
  const int g = lane >> 4;

  const int srow = tid >> 3;
  const int sc = tid & 7;
  int gr0 = r0 + srow;       if (gr0 >= N_NODES) gr0 = N_NODES - 1;
  int gr1 = r0 + srow + 32;  if (gr1 >= N_NODES) gr1 = N_NODES - 1;
  const float* xp0 = x + (size_t)gr0 * IN_C;
  const float* xp1 = x + (size_t)gr1 * IN_C;
  const int ws0 = srow * 8 + (sc ^ (srow & 7));
  const int ws1 = (srow + 32) * 8 + (sc ^ (srow & 7));

  f32x4 acc[4][4];
  {
    const int bcol0 = (w << 6) + fr;
#pragma unroll
    for (int s = 0; s < 4; ++s) {
      float bv = b1[bcol0 + s * 16];
#pragma unroll
      for (int mi = 0; mi < 4; ++mi) acc[mi][s] = (f32x4){bv, bv, bv, bv};
    }
  }

  float4 pA0, pA1, pB0, pB1;
  bf16x8 bhv[2][4];

#define STAGE_LOAD0(T)                                                     \
  { const int kb = (T) * 32 + sc * 4;                                      \
    if ((T) < NT - 1) { pA0 = *(const float4*)(xp0 + kb);                  \
                        pA1 = *(const float4*)(xp1 + kb); }                \
    else { float t0[4], t1[4];                                             \
      _Pragma("unroll") for (int j = 0; j < 4; ++j) { int k = kb + j;      \
        t0[j] = (k < IN_C) ? xp0[k] : 0.f; t1[j] = (k < IN_C) ? xp1[k] : 0.f; } \
      pA0 = (float4){t0[0], t0[1], t0[2], t0[3]};                          \
      pA1 = (float4){t1[0], t1[1], t1[2], t1[3]}; } }

#define STAGE_LOAD1(T)                                                     \
  { const int kb = (T) * 32 + sc * 4;                                      \
    if ((T) < NT - 1) { pB0 = *(const float4*)(xp0 + kb);                  \
                        pB1 = *(const float4*)(xp1 + kb); }                \
    else { float t0[4], t1[4];                                             \
      _Pragma("unroll") for (int j = 0; j < 4; ++j) { int k = kb + j;      \
        t0[j] = (k < IN_C) ? xp0[k] : 0.f; t1[j] = (k < IN_C) ? xp1[k] : 0.f; } \
      pB0 = (float4){t0[0], t0[1], t0[2], t0[3]};                          \
      pB1 = (float4){t1[0], t1[1], t1[2], t1[3]}; } }

#define STAGE_WRITE0(BW) { xt[(BW) * 512 + ws0] = pA0; xt[(BW) * 512 + ws1] = pA1; }
#define STAGE_WRITE1(BW) { xt[(BW) * 512 + ws0] = pB0; xt[(BW) * 512 + ws1] = pB1; }

#define LOADB(T, PAR)                                                      \
  { const size_t tb = (size_t)(T) * 8192;                                  \
    _Pragma("unroll") for (int s = 0; s < 4; ++s) {                        \
      const int n4 = (((w << 6) + s * 16 + fr) << 2) + g;                  \
      bhv[PAR][s] = *(const bf16x8*)(Whf + tb + n4 * 8);                   \
    } }

#define COMPUTE(BR, PAR)                                                   \
  { _Pragma("unroll") for (int mi = 0; mi < 4; ++mi) {                     \
      const int rr = mi * 16 + fr;                                         \
      float4 pa = xt[(BR) * 512 + rr * 8 + ((2 * g) ^ (fr & 7))];          \
      float4 pb = xt[(BR) * 512 + rr * 8 + ((2 * g + 1) ^ (fr & 7))];      \
      union { unsigned u[4]; bf16x8 v; } hh, ll;                           \
      asm("v_cvt_pk_bf16_f32 %0, %1, %2" : "=v"(hh.u[0]) : "v"(pa.x), "v"(pa.y)); \
      asm("v_cvt_pk_bf16_f32 %0, %1, %2" : "=v"(hh.u[1]) : "v"(pa.z), "v"(pa.w)); \
      asm("v_cvt_pk_bf16_f32 %0, %1, %2" : "=v"(hh.u[2]) : "v"(pb.x), "v"(pb.y)); \
      asm("v_cvt_pk_bf16_f32 %0, %1, %2" : "=v"(hh.u[3]) : "v"(pb.z), "v"(pb.w)); \
      float l0 = pa.x - bflo(hh.u[0]), l1 = pa.y - bfhi(hh.u[0]);          \
      float l2 = pa.z - bflo(hh.u[1]), l3 = pa.w - bfhi(hh.u[1]);          \
      float l4 = pb.x - bflo(hh.u[2]), l5 = pb.y - bfhi(hh.u[2]);          \
      float l6 = pb.z - bflo(hh.u[3]), l7 = pb.w - bfhi(hh.u[3]);          \
      asm("v_cvt_pk_bf16_f32 %0, %1, %2" : "=v"(ll.u[0]) : "v"(l0), "v"(l1)); \
      asm("v_cvt_pk_bf16_f32 %0, %1, %2" : "=v"(ll.u[1]) : "v"(l2), "v"(l3)); \
      asm("v_cvt_pk_bf16_f32 %0, %1, %2" : "=v"(ll.u[2]) : "v"(l4), "v"(l5)); \
      asm("v_cvt_pk_bf16_f32 %0, %1, %2" : "=v"(ll.u[3]) : "v"(l6), "v"(l7)); \
      _Pragma("unroll") for (int s = 0; s < 4; ++s) {                      \
        acc[mi][s] = __builtin_amdgcn_mfma_f32_16x16x32_bf16(              \
            hh.v, bhv[PAR][s], acc[mi][s], 0, 0, 0);                       \
        acc[mi][s] = __builtin_amdgcn_mfma_f32_16x16x32_bf16(              \
            ll.v, bhv[PAR][s], acc[mi][s], 0, 0, 0);                       \
      } } }

#define BODY(T, PAR)                                                       \
  { int bW = bR + 1; if (bW == 3) bW = 0;                                  \
    if ((T) + 1 < NT) {                                                    \
      if ((PAR) == 0) STAGE_WRITE1(bW) else STAGE_WRITE0(bW);              \
      if ((T) + 3 < NT) { if ((PAR) == 0) STAGE_LOAD1((T) + 3)             \
                          else STAGE_LOAD0((T) + 3); }                     \
      LOADB((T) + 1, (PAR) ^ 1);                                           \
    }                                                                      \
    COMPUTE(bR, PAR);                                                      \
    __syncthreads();                                                       \
    bR = bW; }

  STAGE_LOAD0(0);
  STAGE_WRITE0(0);
  STAGE_LOAD1(1);
  STAGE_LOAD0(2);
  LOADB(0, 0);
  __syncthreads();

  int bR = 0;
  for (int t = 0; t + 1 < NT; t += 2) {
    BODY(t, 0);
    BODY(t + 1, 1);
  }
  BODY(NT - 1, 0);  // NT odd: tail tile, parity 0

  // epilogue: coalesced h1 store via 2 LDS chunks of 32 rows
#pragma unroll
  for (int ch = 0; ch < 2; ++ch) {
#pragma unroll
    for (int mi2 = 0; mi2 < 2; ++mi2) {
      const int mi = ch * 2 + mi2;
#pragma unroll
      for (int s = 0; s < 4; ++s)
#pragma unroll
        for (int q = 0; q < 4; ++q) {
          int rr = mi2 * 16 + (g << 2) + q;
          int cc = (w << 6) + s * 16 + fr;
          h1t[rr * 264 + cc] = f2bf(fmaxf(acc[mi][s][q], 0.f));
        }
    }
    __syncthreads();
    {
      const int row = tid >> 3, seg = tid & 7;
      const int gr = r0 + ch * 32 + row;
      if (gr < N_NODES) {
        const uint4* src = (const uint4*)&h1t[row * 264 + seg * 32];
        uint4* dst = (uint4*)(h1g + (size_t)gr * 256 + seg * 32);
        dst[0] = src[0];
        dst[1] = src[1];
        dst[2] = src[2];
        dst[3] = src[3];
      }
    }
    __syncthreads();
  }
}

// ------- GEMM2 + L2 norm: H0 = normalize(h1 @ W2^T + b2), bf16 out -------
__global__ __launch_bounds__(256) void gemm2_kernel(
    const unsigned short* __restrict__ h1g,
    const unsigned short* __restrict__ W2hf,
    const unsigned short* __restrict__ W2lf,
    const float* __restrict__ b2,
    unsigned short* __restrict__ H0) {
  const int tid = threadIdx.x;
  const int lane = tid & 63;
  const int w = tid >> 6;
  const int fr = lane & 15;
  const int g = lane >> 4;
  const int wr0 = blockIdx.x * 64 + w * 16;

  f32x4 acc[3];
#pragma unroll
  for (int s = 0; s < 3; ++s) {
    int c = s * 16 + fr;
    float bv = (c < OUTC) ? b2[c] : 0.f;
    acc[s] = (f32x4){bv, bv, bv, bv};
  }

  int ar = wr0 + fr;
  if (ar >= N_NODES) ar = N_NODES - 1;
  const unsigned short* ap = h1g + (size_t)ar * 256 + g * 8;

#pragma unroll
  for (int ks = 0; ks < 8; ++ks) {
    bf16x8 a = *(const bf16x8*)(ap + ks * 32);
#pragma unroll
    for (int s = 0; s < 3; ++s) {
      const int n4 = (((s * 16 + fr) << 2) + g) << 3;
      bf16x8 bh = *(const bf16x8*)(W2hf + (size_t)ks * 1536 + n4);
      bf16x8 bl = *(const bf16x8*)(W2lf + (size_t)ks * 1536 + n4);
      acc[s] = __builtin_amdgcn_mfma_f32_16x16x32_bf16(a, bh, acc[s], 0, 0, 0);
      acc[s] = __builtin_amdgcn_mfma_f32_16x16x32_bf16(a, bl, acc[s], 0, 0, 0);
    }
  }

  float ps[4];
#pragma unroll
  for (int q = 0; q < 4; ++q)
    ps[q] = acc[0][q] * acc[0][q] + acc[1][q] * acc[1][q] + acc[2][q] * acc[2][q];
#pragma unroll
  for (int m = 1; m < 16; m <<= 1)
#pragma unroll
    for (int q = 0; q < 4; ++q) ps[q] += __shfl_xor(ps[q], m);

#pragma unroll
  for (int q = 0; q < 4; ++q) {
    const int gr = wr0 + (g << 2) + q;
    if (gr < N_NODES) {
      float rn = 1.f / fmaxf(sqrtf(ps[q]), 1e-12f);
#pragma unroll
      for (int s = 0; s < 3; ++s)
        H0[(size_t)gr * HSTR + s * 16 + fr] = f2bf(acc[s][q] * rn);
      H0[(size_t)gr * HSTR + 48 + fr] = 0;
    }
  }
}

// ------- bf16 H0 -> fp8 H0 (row = 16 uints = 64 B) -----------------------
__global__ __launch_bounds__(256) void cvt8_kernel(const unsigned* __restrict__ h0b,
                                                   unsigned* __restrict__ h0f) {
  int idx = blockIdx.x * 256 + threadIdx.x;
  if (idx >= N_NODES * 16) return;
  int n = idx >> 4, j = idx & 15;
  unsigned hu0 = h0b[(size_t)n * 32 + 2 * j];
  unsigned hu1 = h0b[(size_t)n * 32 + 2 * j + 1];
  int pk = __builtin_amdgcn_cvt_pk_fp8_f32(bflo(hu0), bfhi(hu0), 0, false);
  pk = __builtin_amdgcn_cvt_pk_fp8_f32(bflo(hu1), bfhi(hu1), pk, true);
  h0f[idx] = (unsigned)pk;
}

// ---------------- exclusive scan (3 kernels) ----------------
__global__ __launch_bounds__(256) void scan1_kernel(const unsigned* __restrict__ deg,
                                                    unsigned* __restrict__ offs,
                                                    unsigned* __restrict__ btot) {
  __shared__ unsigned wsum[4];
  __shared__ unsigned wbase[4];
  const int t = threadIdx.x, lane = t & 63, w = t >> 6;
  const int base = blockIdx.x * 1024 + t * 4;
  unsigned v[4];
#pragma unroll
  for (int i = 0; i < 4; ++i) {
    int idx = base + i;
    v[i] = (idx < N_NODES) ? deg[idx] : 0u;
  }
  unsigned tsum = v[0] + v[1] + v[2] + v[3];
  unsigned inc = tsum;
  for (int d = 1; d < 64; d <<= 1) {
    unsigned n = (unsigned)__shfl_up((int)inc, d);
    if (lane >= d) inc += n;
  }
  if (lane == 63) wsum[w] = inc;
  __syncthreads();
  if (t == 0) {
    unsigned run = 0;
    for (int i = 0; i < 4; ++i) { unsigned s = wsum[i]; wbase[i] = run; run += s; }
    btot[blockIdx.x] = run;
  }
  __syncthreads();
  unsigned ex = wbase[w] + inc - tsum;
#pragma unroll
  for (int i = 0; i < 4; ++i) {
    int idx = base + i;
    if (idx < N_NODES) offs[idx] = ex;
    ex += v[i];
  }
}

__global__ __launch_bounds__(128) void scan2_kernel(const unsigned* __restrict__ btot,
                                                    unsigned* __restrict__ bbase, int B) {
  __shared__ unsigned wsum[2];
  __shared__ unsigned wbase[2];
  const int t = threadIdx.x, lane = t & 63, w = t >> 6;
  unsigned v = (t < B) ? btot[t] : 0u;
  unsigned inc = v;
  for (int d = 1; d < 64; d <<= 1) {
    unsigned n = (unsigned)__shfl_up((int)inc, d);
    if (lane >= d) inc += n;
  }
  if (lane == 63) wsum[w] = inc;
  __syncthreads();
  if (t == 0) {
    unsigned run = 0;
    for (int i = 0; i < 2; ++i) { unsigned s = wsum[i]; wbase[i] = run; run += s; }
  }
  __syncthreads();
  unsigned ex = wbase[w] + inc - v;
  if (t < B) bbase[t] = ex;
}

__global__ __launch_bounds__(256) void scan3_kernel(unsigned* __restrict__ offs,
                                                    const unsigned* __restrict__ bbase) {
  int i = blockIdx.x * 256 + threadIdx.x;
  if (i < N_NODES) offs[i] += bbase[i >> 10];
}

// ---------------- CSC scatter ----------------
__global__ __launch_bounds__(256) void scatter_kernel(const int* __restrict__ row,
                                                      const int* __restrict__ col,
                                                      const float* __restrict__ dinv,
                                                      const unsigned* __restrict__ offs,
                                                      unsigned* __restrict__ cursor,
                                                      int2* __restrict__ rec) {
  int e = blockIdx.x * 256 + threadIdx.x;
  if (e >= N_EDGES) return;
  int r = row[e], c = col[e];
  float wgt = dinv[r] * dinv[c];
  unsigned pos = offs[c] + atomicAdd(&cursor[c], 1u);
  rec[pos] = make_int2(r, __float_as_int(wgt));
}

// ----- APPNP iteration: fp8 rows (64 B), 4 nodes/wave ---------------------
__global__ __launch_bounds__(256) void prop_kernel(
    const unsigned* __restrict__ hsrc,   // fp8 rows, 16 uints/row
    const unsigned* __restrict__ h0b,    // bf16 H0, 32 uints/row
    unsigned* __restrict__ hdst,         // fp8 rows (when fout == nullptr)
    float* __restrict__ fout,            // non-null on last iteration
    const int2* __restrict__ rec,
    const unsigned* __restrict__ offs,
    const unsigned* __restrict__ deg,
    const float* __restrict__ dinv) {
  const int wv = threadIdx.x >> 6;
  const int lane = threadIdx.x & 63;
  const int q = lane >> 4;             // quarter: which node
  const int sub = lane & 15;           // uint index within 64-B row
  const int n = blockIdx.x * 16 + wv * 4 + q;
  if (n >= N_NODES) return;
  const unsigned s = offs[n];
  const unsigned e = s + deg[n];
  float a0 = 0.f, a1 = 0.f, a2 = 0.f, a3 = 0.f;
  float c0 = 0.f, c1 = 0.f, c2 = 0.f, c3 = 0.f;

#define ACC8(U, W, A0, A1, A2, A3)                                        \
  { f32x2 lo = __builtin_amdgcn_cvt_pk_f32_fp8((int)(U), false);          \
    f32x2 hi = __builtin_amdgcn_cvt_pk_f32_fp8((int)(U), true);           \
    A0 += lo.x * (W); A1 += lo.y * (W);                                   \
    A2 += hi.x * (W); A3 += hi.y * (W); }

  unsigned i = s;
  for (; i + 8 <= e; i += 8) {
    int2 r0 = rec[i],     r1 = rec[i + 1], r2 = rec[i + 2], r3 = rec[i + 3];
    int2 r4 = rec[i + 4], r5 = rec[i + 5], r6 = rec[i + 6], r7 = rec[i + 7];
    unsigned u0 = hsrc[(size_t)r0.x * 16 + sub];
    unsigned u1 = hsrc[(size_t)r1.x * 16 + sub];
    unsigned u2 = hsrc[(size_t)r2.x * 16 + sub];
    unsigned u3 = hsrc[(size_t)r3.x * 16 + sub];
    unsigned u4 = hsrc[(size_t)r4.x * 16 + sub];
    unsigned u5 = hsrc[(size_t)r5.x * 16 + sub];
    unsigned u6 = hsrc[(size_t)r6.x * 16 + sub];
    unsigned u7 = hsrc[(size_t)r7.x * 16 + sub];
    ACC8(u0, __int_as_float(r0.y), a0, a1, a2, a3);
    ACC8(u1, __int_as_float(r1.y), c0, c1, c2, c3);
    ACC8(u2, __int_as_float(r2.y), a0, a1, a2, a3);
    ACC8(u3, __int_as_float(r3.y), c0, c1, c2, c3);
    ACC8(u4, __int_as_float(r4.y), a0, a1, a2, a3);
    ACC8(u5, __int_as_float(r5.y), c0, c1, c2, c3);
    ACC8(u6, __int_as_float(r6.y), a0, a1, a2, a3);
    ACC8(u7, __int_as_float(r7.y), c0, c1, c2, c3);
  }
  for (; i < e; ++i) {
    int2 r = rec[i];
    unsigned u = hsrc[(size_t)r.x * 16 + sub];
    ACC8(u, __int_as_float(r.y), a0, a1, a2, a3);
  }
  // self-loop
  {
    float di = dinv[n];
    float wself = di * di;
    unsigned su = hsrc[(size_t)n * 16 + sub];
    ACC8(su, wself, a0, a1, a2, a3);
  }
  // alpha * h0 (bf16-exact)
  unsigned hu0 = h0b[(size_t)n * 32 + 2 * sub];
  unsigned hu1 = h0b[(size_t)n * 32 + 2 * sub + 1];
  float o0 = 0.9f * (a0 + c0) + 0.1f * bflo(hu0);
  float o1 = 0.9f * (a1 + c1) + 0.1f * bfhi(hu0);
  float o2 = 0.9f * (a2 + c2) + 0.1f * bflo(hu1);
  float o3 = 0.9f * (a3 + c3) + 0.1f * bfhi(hu1);
  if (fout) {
    int c = 4 * sub;
    if (c < OUTC)     fout[(size_t)n * OUTC + c] = o0;
    if (c + 1 < OUTC) fout[(size_t)n * OUTC + c + 1] = o1;
    if (c + 2 < OUTC) fout[(size_t)n * OUTC + c + 2] = o2;
    if (c + 3 < OUTC) fout[(size_t)n * OUTC + c + 3] = o3;
  } else {
    int pk = __builtin_amdgcn_cvt_pk_fp8_f32(o0, o1, 0, false);
    pk = __builtin_amdgcn_cvt_pk_fp8_f32(o2, o3, pk, true);
    hdst[(size_t)n * 16 + sub] = (unsigned)pk;
  }
}

// ---------------- host ----------------
extern "C" void kernel_launch(void* const* d_in, const int* in_sizes, int n_in,
                              void* d_out, int out_size, void* d_ws, size_t ws_size,
                              hipStream_t stream) {
  const float* x  = (const float*)d_in[0];
  const int*   ei = (const int*)d_in[1];
  const float* W1 = (const float*)d_in[2];
  const float* b1 = (const float*)d_in[3];
  const float* W2 = (const float*)d_in[4];
  const float* b2 = (const float*)d_in[5];
  float* out = (float*)d_out;

  char* p = (char*)d_ws;
  auto alloc = [&](size_t bytes) {
    char* q = p;
    p += (bytes + 255) & ~(size_t)255;
    return q;
  };
  unsigned* deg    = (unsigned*)alloc((size_t)N_NODES * 4);
  float*    dinv   = (float*)   alloc((size_t)N_NODES * 4);
  unsigned* offs   = (unsigned*)alloc((size_t)N_NODES * 4);
  unsigned* btot   = (unsigned*)alloc(128 * 4);
  unsigned* bbase  = (unsigned*)alloc(128 * 4);
  unsigned* cursor = (unsigned*)alloc((size_t)N_NODES * 4);
  int2*     rec    = (int2*)    alloc((size_t)N_EDGES * 8);
  unsigned short* H0b = (unsigned short*)alloc((size_t)N_NODES * HSTR * 2);
  unsigned* H0f = (unsigned*)alloc((size_t)N_NODES * 16 * 4);
  unsigned* HA  = (unsigned*)alloc((size_t)N_NODES * 16 * 4);
  unsigned* HB  = (unsigned*)alloc((size_t)N_NODES * 16 * 4);
  unsigned short* h1g = (unsigned short*)alloc((size_t)N_NODES * HID_C * 2);
  unsigned short* Whf = (unsigned short*)alloc((size_t)NT * 8192 * 2);
  unsigned short* W2hf = (unsigned short*)alloc((size_t)8 * 1536 * 2);
  unsigned short* W2lf = (unsigned short*)alloc((size_t)8 * 1536 * 2);

  const int* row = ei;            // edge_index[0] : sources
  const int* col = ei + N_EDGES;  // edge_index[1] : targets

  hipMemsetAsync(deg, 0, (size_t)N_NODES * 4, stream);
  hipMemsetAsync(cursor, 0, (size_t)N_NODES * 4, stream);

  deg_kernel<<<(N_EDGES + 255) / 256, 256, 0, stream>>>(col, deg);
  dinv_kernel<<<(N_NODES + 255) / 256, 256, 0, stream>>>(deg, dinv);
  wprep1_kernel<<<(HID_C * KPAD + 255) / 256, 256, 0, stream>>>(W1, Whf);
  wprep2_kernel<<<(48 * HID_C + 255) / 256, 256, 0, stream>>>(W2, W2hf, W2lf);
  gemm1_kernel<<<(N_NODES + 63) / 64, 256, 0, stream>>>(x, Whf, b1, h1g);
  gemm2_kernel<<<(N_NODES + 63) / 64, 256, 0, stream>>>(h1g, W2hf, W2lf, b2, H0b);
  cvt8_kernel<<<(N_NODES * 16 + 255) / 256, 256, 0, stream>>>((const unsigned*)H0b, H0f);

  const int B = (N_NODES + 1023) / 1024;  // 98
  scan1_kernel<<<B, 256, 0, stream>>>(deg, offs, btot);
  scan2_kernel<<<1, 128, 0, stream>>>(btot, bbase, B);
  scan3_kernel<<<(N_NODES + 255) / 256, 256, 0, stream>>>(offs, bbase);
  scatter_kernel<<<(N_EDGES + 255) / 256, 256, 0, stream>>>(row, col, dinv, offs, cursor, rec);

  const unsigned* src = H0f;
  unsigned* bufs[2] = {HA, HB};
  for (int k = 0; k < K_ITERS; ++k) {
    bool last = (k == K_ITERS - 1);
    unsigned* dst = last ? nullptr : bufs[k & 1];
    float* fdst = last ? out : nullptr;
    prop_kernel<<<(N_NODES + 15) / 16, 256, 0, stream>>>(
        src, (const unsigned*)H0b, dst, fdst, rec, offs, deg, dinv);
    src = dst;
  }
}